// Round 5
// baseline (1195.163 us; speedup 1.0000x reference)
//
#include <hip/hip_runtime.h>
#include <hip/hip_bf16.h>
#include <stdint.h>

#define NB 512
#define NW 40
#define NE 512
#define NH 512
#define NV 12000
#define G4 2048

typedef unsigned short u16;
typedef unsigned int u32;
typedef unsigned long long u64;
typedef __attribute__((ext_vector_type(8))) short short8;
typedef __attribute__((ext_vector_type(4))) float f32x4;

__device__ __forceinline__ unsigned short f2bf(float f) {
  unsigned int u = __float_as_uint(f);
  u += 0x7FFF + ((u >> 16) & 1);
  return (unsigned short)(u >> 16);
}
__device__ __forceinline__ float bf2f(unsigned short b) {
  return __uint_as_float(((unsigned int)b) << 16);
}
__device__ __forceinline__ float loadIn(const void* p, long i, int bf) {
  return bf ? bf2f(((const u16*)p)[i]) : ((const float*)p)[i];
}
__device__ __forceinline__ float fast_tanh(float x) {
  float ax = __builtin_fabsf(x);
  float t = 1.f - 2.f * __builtin_amdgcn_rcpf(__expf(ax + ax) + 1.f);
  return __builtin_copysignf(t, x);
}
__device__ __forceinline__ float sigm(float x) {
  return __builtin_amdgcn_rcpf(1.f + __expf(-x));
}

// ---------------- dtype detector ----------------
__global__ void detect_kernel(const u16* p, int* flag) {
  __shared__ int cnt;
  int i = threadIdx.x;
  if (i == 0) cnt = 0;
  __syncthreads();
  unsigned short u = p[2 * (i * 1001)];
  int e = (u >> 7) & 0xFF;
  if (e >= 100 && e <= 126) atomicAdd(&cnt, 1);
  __syncthreads();
  if (i == 0) *flag = (cnt >= 32) ? 1 : 0;
}

// ---------------- tableT = bf16(tanh(lookup_W^T)), (V, E) ----------------
__global__ void table_kernel(const void* lookup, const int* flag, u16* tableT) {
  __shared__ float tile[64][65];
  int bf = *flag;
  int v0 = blockIdx.x * 64, e0 = blockIdx.y * 64;
  int tx = threadIdx.x, ty = threadIdx.y;  // (64,4)
#pragma unroll
  for (int r = 0; r < 16; ++r) {
    int e = r * 4 + ty, v = tx;
    if (v0 + v < NV)
      tile[e][v] = tanhf(loadIn(lookup, (long)(e0 + e) * NV + v0 + v, bf));
  }
  __syncthreads();
#pragma unroll
  for (int r = 0; r < 16; ++r) {
    int v = r * 4 + ty, e = tx;
    if (v0 + v < NV)
      tableT[(long)(v0 + v) * NE + e0 + e] = f2bf(tile[e][v]);
  }
}

// ---------------- embf: emb in MFMA A-fragment layout ----------------
// embf[((tq*32 + bt)*16 + kp)*512 + l*8 + e] = tanh-emb[b = bt*16+(l&15)]
//                                              [k = kp*32+(l>>4)*8+e]
__global__ void embed_kernel(const int* __restrict__ qv,
                             const u16* __restrict__ tableT,
                             u16* __restrict__ embf) {
  long g = (long)blockIdx.x * 256 + threadIdx.x;  // [0, 40*32*16*64)
  int l = (int)(g & 63);
  int kp = (int)((g >> 6) & 15);
  int bt = (int)((g >> 10) & 31);
  int tq = (int)(g >> 15);
  int col = l & 15, quad = l >> 4;
  int b = bt * 16 + col;
  int q = qv[b * NW + tq];
  uint4 val = make_uint4(0u, 0u, 0u, 0u);
  if (q > 0)
    val = *(const uint4*)(tableT + (long)(q - 1) * NE + kp * 32 + quad * 8);
  *(uint4*)(embf + g * 8) = val;
}

// ---------------- pack weights ----------------
// Wc[d] rows = [wih | whh] (row-major, swizzle-free source for LDS loaders)
// Wx1h = wih1 k in [512,1024) in B-fragment layout:
//   Wx1h[((((d*32+jb)*4+g)*16+kp)*512 + l*8 + e] =
//     wih1[d][g*512+jb*16+(l&15)][512 + kp*32 + (l>>4)*8 + e]
__global__ void pack_kernel(const void* wih0, const void* whh0, const void* b0,
                            const void* wih1, const void* whh1, const void* b1,
                            const int* flag, u16* Wc0, u16* Wc1, float* bsum,
                            u16* Wx1h) {
  const long N0 = 2L * G4 * 1024, N1 = 2L * G4 * 1536;
  const long NB2 = 2L * 2 * G4;
  const long N2 = 2L * 32 * 4 * 16 * 512;  // Wx1h: 2,097,152
  long idx = (long)blockIdx.x * 256 + threadIdx.x;
  int bf = *flag;
  if (idx < N0) {
    int d = (int)(idx / (G4 * 1024));
    int rem = (int)(idx % (long)(G4 * 1024));
    int g = rem / 1024, k = rem % 1024;
    float v = (k < 512) ? loadIn(wih0, ((long)d * G4 + g) * 512 + k, bf)
                        : loadIn(whh0, ((long)d * G4 + g) * 512 + (k - 512), bf);
    Wc0[idx] = f2bf(v);
  } else if (idx < N0 + N1) {
    long i2 = idx - N0;
    int d = (int)(i2 / (G4 * 1536));
    int rem = (int)(i2 % (long)(G4 * 1536));
    int g = rem / 1536, k = rem % 1536;
    float v = (k < 1024) ? loadIn(wih1, ((long)d * G4 + g) * 1024 + k, bf)
                         : loadIn(whh1, ((long)d * G4 + g) * 512 + (k - 1024), bf);
    Wc1[i2] = f2bf(v);
  } else if (idx < N0 + N1 + NB2) {
    long i3 = idx - N0 - N1;  // [layer][d][g]
    int layer = (int)(i3 / (2 * G4));
    int d = (int)((i3 / G4) & 1);
    int g = (int)(i3 % G4);
    const void* bb = layer ? b1 : b0;
    float v = loadIn(bb, (long)d * 2 * G4 + g, bf) +
              loadIn(bb, (long)d * 2 * G4 + G4 + g, bf);
    bsum[i3] = v;
  } else if (idx < N0 + N1 + NB2 + N2) {
    long i4 = idx - N0 - N1 - NB2;
    int e = (int)(i4 & 7);
    int l = (int)((i4 >> 3) & 63);
    int kp = (int)((i4 >> 9) & 15);
    int g = (int)((i4 >> 13) & 3);
    int jb = (int)((i4 >> 15) & 31);
    int d = (int)(i4 >> 20);
    int col = l & 15, quad = l >> 4;
    float v = loadIn(wih1,
                     ((long)d * G4 + g * 512 + jb * 16 + col) * 1024 + 512 +
                         kp * 32 + quad * 8 + e,
                     bf);
    Wx1h[i4] = f2bf(v);
  }
}

// ---------------- zero the barrier (8 KB) ----------------
__global__ void zero_bar(unsigned int* bar) {
  bar[blockIdx.x * 256 + threadIdx.x] = 0u;
}

// ---------------- fused persistent bidirectional LSTM ----------------
// R13: the xg GEMM is fused into the recurrence and placed in the dead
// window before the per-step rendezvous (it is poll-independent work).
// Geometry: 256 blocks = (mi 4: 128 batch rows) x (d 2) x (cb 32: 16 cols).
//  * LDS: Wih slice 64K (l0 full; l1 k<512) + Whh slice 64K + 32K h-stage
//    dbuf = 160 KiB. Both W slices resident for the whole dispatch.
//  * x-part: A-frags from fragment-layout embf/h0f (coalesced 1KB reg
//    loads, no LDS, no barriers); B from LDS Wih (l1 k>=512: from Wx1h
//    fragment-layout global, coalesced). 8 MFMA per kp into accX.
//  * h-part: R8-proven staged dance (8x16KB chunks, dbuf, barriers),
//    accumulating into accA (= accX of previous xpart call + bias at cell).
//  * rendezvous: R8's fetch_add+flag per (mi,d) clique, 32 writers.
// Deleted: xg buffer (168 MB), 2x xg_gemm dispatches, 336 MB HBM traffic.
__global__ __launch_bounds__(256, 1) void lstm_pers(
    const u16* __restrict__ Xf, int KPX, const u16* __restrict__ Wxh,
    const u16* __restrict__ Wc, int Kfull, int Kx, u16* __restrict__ hbuf,
    u16* __restrict__ h0f, void* __restrict__ outp,
    const int* __restrict__ qlen, const int* __restrict__ flag,
    const float* __restrict__ bsumL, unsigned int* bar, int layer) {
  __shared__ __align__(16) char lds[163840];  // [Wih 64K][Whh 64K][stage 2x16K]
  const int tid = threadIdx.x;
  const int lane = tid & 63, wv = tid >> 6;
  const int col = lane & 15, quad = lane >> 4;
  const int l = blockIdx.x;
  const int cb = l & 31;   // 16-col slice
  const int gid = l >> 5;  // (mi,d) clique: d = gid&1, mi = gid>>1
  const int d = gid & 1, mi = gid >> 1;
  const int j0 = cb * 16;
  const int m0 = mi * 128;

  // ---- preload W slices: region 0 = Wih (k base 0), 1 = Whh (k base Kx) --
  // LDS row rr = g*16+jn holds W row g*512+j0+jn; within-row 8x64k chunks,
  // 16B slots XOR-swizzled by ((rr&7)<<3).
#pragma unroll
  for (int rg = 0; rg < 2; ++rg) {
    int base_k = rg ? Kx : 0;
    char* dstb = lds + rg * 65536;
#pragma unroll
    for (int p = 0; p < 16; ++p) {
      int c = p * 256 + tid;
      int row = c >> 6, rem = c & 63;
      int kc = rem >> 3, sl = rem & 7;
      int gk = base_k + kc * 64 + ((sl * 8) ^ ((row & 7) << 3));
      const u16* gsrc =
          Wc + ((long)d * G4 + (row >> 4) * 512 + j0 + (row & 15)) * Kfull + gk;
      __builtin_amdgcn_global_load_lds(
          (const __attribute__((address_space(1))) void*)(const void*)gsrc,
          (__attribute__((address_space(3))) void*)(dstb + p * 4096 +
                                                    wv * 1024),
          16, 0, 0);
    }
  }
  const u16* WihS = (const u16*)lds;
  const u16* WhhS = (const u16*)(lds + 65536);
  char* hstg = lds + 131072;  // 2 x 16 KB h-stage dbuf
  u16* hLDS = (u16*)hstg;     // h-pack [128 m][16 jn] = 4 KB aliases buf0

  float biasv[4];
#pragma unroll
  for (int g = 0; g < 4; ++g)
    biasv[g] = bsumL[d * G4 + g * 512 + j0 + col];

  float creg[2][4];
#pragma unroll
  for (int i = 0; i < 2; ++i)
#pragma unroll
    for (int r = 0; r < 4; ++r) creg[i][r] = 0.f;
  const int isbf = *flag;
  f32x4 zero = {0.f, 0.f, 0.f, 0.f};
  f32x4 accX[2][4];

  __syncthreads();  // W slices resident

  // ---- x-part: gates_x(tq) = X @ Wih^T into accX (reg-only, no barriers) -
  auto xpart = [&](int tq) {
#pragma unroll
    for (int i = 0; i < 2; ++i)
#pragma unroll
      for (int g = 0; g < 4; ++g) accX[i][g] = zero;
    const u16* Ab = Xf + (((long)tq * 32 + mi * 8 + wv * 2) * KPX) * 512 +
                    lane * 8;
    // k < 512: B from LDS Wih
#pragma unroll 2
    for (int kp = 0; kp < 16; ++kp) {
      short8 ax0 = *(const short8*)(Ab + (long)kp * 512);
      short8 ax1 = *(const short8*)(Ab + ((long)KPX + kp) * 512);
      int off = (kp & 1) * 32 + quad * 8;
#pragma unroll
      for (int g = 0; g < 4; ++g) {
        int br = g * 16 + col;
        short8 bx = *(const short8*)(WihS + br * 512 + (kp >> 1) * 64 +
                                     (off ^ ((br & 7) << 3)));
        accX[0][g] =
            __builtin_amdgcn_mfma_f32_16x16x32_bf16(ax0, bx, accX[0][g], 0, 0, 0);
        accX[1][g] =
            __builtin_amdgcn_mfma_f32_16x16x32_bf16(ax1, bx, accX[1][g], 0, 0, 0);
      }
    }
    // k >= 512 (layer 1 only): B streamed from fragment-layout Wx1h
    if (KPX > 16) {
      const u16* WxB =
          Wxh + (((long)d * 32 + cb) * 4) * 16 * 512 + lane * 8;
#pragma unroll 2
      for (int kp = 16; kp < 32; ++kp) {
        short8 ax0 = *(const short8*)(Ab + (long)kp * 512);
        short8 ax1 = *(const short8*)(Ab + ((long)KPX + kp) * 512);
#pragma unroll
        for (int g = 0; g < 4; ++g) {
          short8 bx =
              *(const short8*)(WxB + ((long)g * 16 + (kp - 16)) * 512);
          accX[0][g] = __builtin_amdgcn_mfma_f32_16x16x32_bf16(ax0, bx,
                                                               accX[0][g], 0, 0, 0);
          accX[1][g] = __builtin_amdgcn_mfma_f32_16x16x32_bf16(ax1, bx,
                                                               accX[1][g], 0, 0, 0);
        }
      }
    }
  };

  xpart(d ? NW - 1 : 0);

#pragma unroll 1
  for (int t = 0; t < NW; ++t) {
    const int tq = d ? (NW - 1 - t) : t;

    f32x4 accA[2][4];
#pragma unroll
    for (int i = 0; i < 2; ++i)
#pragma unroll
      for (int g = 0; g < 4; ++g) accA[i][g] = accX[i][g];

    if (t > 0) {
      const u16* hp =
          hbuf + ((t - 1) & 1) * (2L * NB * NH) + ((long)d * NB + m0) * NH;
      // stage chunk: 128 rows x 64 k = 16 KB, SC1 (LLC)
      auto stage = [&](int it, int pb) {
        char* dst = hstg + pb * 16384;
#pragma unroll
        for (int p = 0; p < 4; ++p) {
          int c = p * 256 + tid;  // [0,1024)
          int row = c >> 3, slot = c & 7;
          int kk = it * 64 + ((slot * 8) ^ ((row & 7) << 3));
          const u16* gsrc = hp + (long)row * NH + kk;
          __builtin_amdgcn_global_load_lds(
              (const __attribute__((address_space(1))) void*)(const void*)gsrc,
              (__attribute__((address_space(3))) void*)(dst + p * 4096 +
                                                        wv * 1024),
              16, 0, 16 /* SC1 */);
        }
      };
      stage(0, 0);
      __syncthreads();
#pragma unroll 1
      for (int it = 0; it < 8; ++it) {
        if (it + 1 < 8) stage(it + 1, (it + 1) & 1);
        const u16* As = (const u16*)(hstg + (it & 1) * 16384);
#pragma unroll
        for (int ks = 0; ks < 2; ++ks) {
          int ksub = ks * 32 + quad * 8;
          short8 afr[2];
#pragma unroll
          for (int mf = 0; mf < 2; ++mf) {
            int rm = wv * 32 + mf * 16 + col;
            afr[mf] = *(const short8*)(As + rm * 64 + (ksub ^ ((rm & 7) << 3)));
          }
          int kc = it * 64 + ksub;
#pragma unroll
          for (int g = 0; g < 4; ++g) {
            int br = g * 16 + col;
            short8 bfr = *(const short8*)(WhhS + br * 512 + (kc & ~63) +
                                          ((kc & 63) ^ ((br & 7) << 3)));
            accA[0][g] = __builtin_amdgcn_mfma_f32_16x16x32_bf16(
                afr[0], bfr, accA[0][g], 0, 0, 0);
            accA[1][g] = __builtin_amdgcn_mfma_f32_16x16x32_bf16(
                afr[1], bfr, accA[1][g], 0, 0, 0);
          }
        }
        if (it + 1 < 8) __syncthreads();
      }
    }

    // ---- cell update (f32), pack h into 4 KB LDS ----
#pragma unroll
    for (int mf = 0; mf < 2; ++mf)
#pragma unroll
      for (int r = 0; r < 4; ++r) {
        int m = wv * 32 + mf * 16 + quad * 4 + r;
        float gi = accA[mf][0][r] + biasv[0];
        float gf = accA[mf][1][r] + biasv[1];
        float gg = accA[mf][2][r] + biasv[2];
        float go = accA[mf][3][r] + biasv[3];
        float si = sigm(gi);
        float sf = sigm(gf);
        float so = sigm(go);
        float cn = sf * creg[mf][r] + si * fast_tanh(gg);
        float h = so * fast_tanh(cn);
        creg[mf][r] = cn;
        hLDS[m * 16 + col] = f2bf(h);
        if (layer == 1 && !isbf) {
          int bg = m0 + m;
          if (qlen[bg] - 1 == tq)
            ((float*)outp)[(long)bg * (2 * NH) + d * NH + j0 + col] = h;
        }
      }
    __syncthreads();

    // ---- hbuf stores (LLC) + bf16 output rows ----
    u16* hnxt = hbuf + (t & 1) * (2L * NB * NH);
#pragma unroll
    for (int p = 0; p < 4; ++p) {
      int c = p * 256 + tid;  // [0,1024): m = c>>3, pr = c&7
      int m = c >> 3, pr = c & 7;
      u32 hw = ((const u32*)hLDS)[m * 8 + pr];
      int bg = m0 + m;
      __hip_atomic_store((u32*)(hnxt + ((long)d * NB + bg) * NH + j0 + pr * 2),
                         hw, __ATOMIC_RELAXED, __HIP_MEMORY_SCOPE_AGENT);
      if (layer == 1 && isbf && qlen[bg] - 1 == tq)
        *(u32*)((u16*)outp + (long)bg * (2 * NH) + d * NH + j0 + pr * 2) = hw;
    }
    // ---- h0f store (layer 0): fragment layout, 16B/thread coalesced ----
    if (layer == 0) {
      int oct = tid >> 7, m = tid & 127;
      int k0 = d * 512 + j0 + oct * 8;
      int kp = k0 >> 5, qd = (k0 >> 3) & 3;
      int bt = mi * 8 + (m >> 4);
      const u32* sp = (const u32*)hLDS + m * 8 + oct * 4;
      uint4 v = make_uint4(sp[0], sp[1], sp[2], sp[3]);
      *(uint4*)(h0f + (((long)tq * 32 + bt) * 32 + kp) * 512 +
                (qd * 16 + (m & 15)) * 8) = v;
    }

    // ---- x-part for next step: fills the rendezvous window ----
    if (t + 1 < NW) xpart(d ? (NW - 2 - t) : (t + 1));

    // ---- clique rendezvous (32 writers per (mi,d)) ----
    if (t < NW - 1) {
      __syncthreads();  // drains vmcnt: h stores visible at LLC
      if (tid == 0) {
        u32* cnt = &bar[gid * 64];
        u32* flg = &bar[1024 + gid * 64];
        unsigned old = __hip_atomic_fetch_add(cnt, 1u, __ATOMIC_RELAXED,
                                              __HIP_MEMORY_SCOPE_AGENT);
        if (old == 32u * (t + 1) - 1u)
          __hip_atomic_store(flg, (unsigned)(t + 1), __ATOMIC_RELAXED,
                             __HIP_MEMORY_SCOPE_AGENT);
        else
          while (__hip_atomic_load(flg, __ATOMIC_RELAXED,
                                   __HIP_MEMORY_SCOPE_AGENT) <
                 (unsigned)(t + 1))
            __builtin_amdgcn_s_sleep(1);
      }
      __syncthreads();
    }
  }
}

extern "C" void kernel_launch(void* const* d_in, const int* in_sizes, int n_in,
                              void* d_out, int out_size, void* d_ws,
                              size_t ws_size, hipStream_t stream) {
  const int* qv = (const int*)d_in[0];
  const int* ql = (const int*)d_in[1];
  const void* lookup = d_in[2];
  const void* wih0 = d_in[3];
  const void* whh0 = d_in[4];
  const void* b0 = d_in[5];
  const void* wih1 = d_in[6];
  const void* whh1 = d_in[7];
  const void* b1 = d_in[8];

  char* ws = (char*)d_ws;
  size_t off = 0;
  int* flag = (int*)ws;                 off += 256;
  unsigned int* bar = (unsigned int*)(ws + off); off += 8192;
  float* bsum = (float*)(ws + off);     off += 2L * 2 * G4 * 4;        // 32 KB
  u16* Wc0 = (u16*)(ws + off);          off += 2L * G4 * 1024 * 2;     // 8 MB
  u16* Wc1 = (u16*)(ws + off);          off += 2L * G4 * 1536 * 2;     // 12 MB
  u16* Wx1h = (u16*)(ws + off);         off += 2L * 32 * 4 * 16 * 512 * 2; // 4 MB
  u16* hbuf = (u16*)(ws + off);         off += 2L * 2 * NB * NH * 2;   // 2 MB
  u16* h0f = (u16*)(ws + off);          off += (size_t)NW * NB * 2 * NH * 2; // 42 MB
  u16* embf = (u16*)(ws + off);         off += (size_t)NW * NB * NE * 2;     // 21 MB
  u16* tableT = h0f;  // tableT (12.3 MB) aliases h0f: dead before layer0

  detect_kernel<<<1, 64, 0, stream>>>((const u16*)lookup, flag);
  table_kernel<<<dim3(188, 8), dim3(64, 4), 0, stream>>>(lookup, flag, tableT);
  {
    long total = 2L * G4 * 1024 + 2L * G4 * 1536 + 2L * 2 * G4 +
                 2L * 32 * 4 * 16 * 512;
    int blocks = (int)((total + 255) / 256);
    pack_kernel<<<blocks, 256, 0, stream>>>(wih0, whh0, b0, wih1, whh1, b1,
                                            flag, Wc0, Wc1, bsum, Wx1h);
  }
  embed_kernel<<<5120, 256, 0, stream>>>(qv, tableT, embf);

  // layer 0 (fused x-GEMM + recurrence)
  zero_bar<<<8, 256, 0, stream>>>(bar);
  lstm_pers<<<256, 256, 0, stream>>>(embf, 16, Wx1h, Wc0, 1024, 512, hbuf, h0f,
                                     d_out, ql, flag, bsum, bar, 0);
  // layer 1
  zero_bar<<<8, 256, 0, stream>>>(bar);
  lstm_pers<<<256, 256, 0, stream>>>(h0f, 32, Wx1h, Wc1, 1536, 1024, hbuf, h0f,
                                     d_out, ql, flag, bsum + 2 * G4, bar, 1);
}

// Round 6
// 949.233 us; speedup vs baseline: 1.2591x; 1.2591x over previous
//
#include <hip/hip_runtime.h>
#include <hip/hip_bf16.h>
#include <stdint.h>

#define NB 512
#define NW 40
#define NE 512
#define NH 512
#define NV 12000
#define G4 2048

typedef unsigned short u16;
typedef unsigned int u32;
typedef unsigned long long u64;
typedef __attribute__((ext_vector_type(8))) short short8;
typedef __attribute__((ext_vector_type(4))) float f32x4;

__device__ __forceinline__ unsigned short f2bf(float f) {
  unsigned int u = __float_as_uint(f);
  u += 0x7FFF + ((u >> 16) & 1);
  return (unsigned short)(u >> 16);
}
__device__ __forceinline__ float bf2f(unsigned short b) {
  return __uint_as_float(((unsigned int)b) << 16);
}
__device__ __forceinline__ float loadIn(const void* p, long i, int bf) {
  return bf ? bf2f(((const u16*)p)[i]) : ((const float*)p)[i];
}
// exp-based tanh: |err| ~1e-7 abs, saturates cleanly (exp->inf => 1).
__device__ __forceinline__ float fast_tanh(float x) {
  float ax = __builtin_fabsf(x);
  float t = 1.f - 2.f * __builtin_amdgcn_rcpf(__expf(ax + ax) + 1.f);
  return __builtin_copysignf(t, x);
}
__device__ __forceinline__ float sigm(float x) {
  return __builtin_amdgcn_rcpf(1.f + __expf(-x));
}

// ---------------- dtype detector ----------------
__global__ void detect_kernel(const u16* p, int* flag) {
  __shared__ int cnt;
  int i = threadIdx.x;
  if (i == 0) cnt = 0;
  __syncthreads();
  unsigned short u = p[2 * (i * 1001)];
  int e = (u >> 7) & 0xFF;
  if (e >= 100 && e <= 126) atomicAdd(&cnt, 1);
  __syncthreads();
  if (i == 0) *flag = (cnt >= 32) ? 1 : 0;
}

// ---------------- tableT = bf16(tanh(lookup_W^T)), (V, E) ----------------
__global__ void table_kernel(const void* lookup, const int* flag, u16* tableT) {
  __shared__ float tile[64][65];
  int bf = *flag;
  int v0 = blockIdx.x * 64, e0 = blockIdx.y * 64;
  int tx = threadIdx.x, ty = threadIdx.y;  // (64,4)
#pragma unroll
  for (int r = 0; r < 16; ++r) {
    int e = r * 4 + ty, v = tx;
    if (v0 + v < NV)
      tile[e][v] = tanhf(loadIn(lookup, (long)(e0 + e) * NV + v0 + v, bf));
  }
  __syncthreads();
#pragma unroll
  for (int r = 0; r < 16; ++r) {
    int v = r * 4 + ty, e = tx;
    if (v0 + v < NV)
      tableT[(long)(v0 + v) * NE + e0 + e] = f2bf(tile[e][v]);
  }
}

// ---------------- emb (W*B, E) bf16, rows tb = t*NB+b ----------------
__global__ void embed_kernel(const int* __restrict__ qv,
                             const u16* __restrict__ tableT,
                             u16* __restrict__ emb) {
  int tid = blockIdx.x * 256 + threadIdx.x;
  int token = tid >> 6;
  int chunk = tid & 63;
  int tt = token / NB, b = token % NB;
  int q = qv[b * NW + tt];
  uint4 val = make_uint4(0u, 0u, 0u, 0u);
  if (q > 0) val = *(const uint4*)(tableT + (long)(q - 1) * NE + chunk * 8);
  *(uint4*)(emb + (long)token * NE + chunk * 8) = val;
}

// ---------------- pack weights: Wc[d] rows = [wih | whh], bf16 ------------
__global__ void pack_kernel(const void* wih0, const void* whh0, const void* b0,
                            const void* wih1, const void* whh1, const void* b1,
                            const int* flag, u16* Wc0, u16* Wc1, float* bsum) {
  const long N0 = 2L * G4 * 1024, N1 = 2L * G4 * 1536;
  long idx = (long)blockIdx.x * 256 + threadIdx.x;
  int bf = *flag;
  if (idx < N0) {
    int d = (int)(idx / (G4 * 1024));
    int rem = (int)(idx % (long)(G4 * 1024));
    int g = rem / 1024, k = rem % 1024;
    float v = (k < 512) ? loadIn(wih0, ((long)d * G4 + g) * 512 + k, bf)
                        : loadIn(whh0, ((long)d * G4 + g) * 512 + (k - 512), bf);
    Wc0[idx] = f2bf(v);
  } else if (idx < N0 + N1) {
    long i2 = idx - N0;
    int d = (int)(i2 / (G4 * 1536));
    int rem = (int)(i2 % (long)(G4 * 1536));
    int g = rem / 1536, k = rem % 1536;
    float v = (k < 1024) ? loadIn(wih1, ((long)d * G4 + g) * 1024 + k, bf)
                         : loadIn(whh1, ((long)d * G4 + g) * 512 + (k - 1024), bf);
    Wc1[i2] = f2bf(v);
  } else if (idx < N0 + N1 + 2L * 2 * G4) {
    long i3 = idx - N0 - N1;  // [layer][d][g]
    int layer = (int)(i3 / (2 * G4));
    int d = (int)((i3 / G4) & 1);
    int g = (int)(i3 % G4);
    const void* bb = layer ? b1 : b0;
    float v = loadIn(bb, (long)d * 2 * G4 + g, bf) +
              loadIn(bb, (long)d * 2 * G4 + G4 + g, bf);
    bsum[i3] = v;
  }
}

// ---------------- zero the barrier (8 KB) ----------------
__global__ void zero_bar(unsigned int* bar) {
  bar[blockIdx.x * 256 + threadIdx.x] = 0u;
}

// ---------------- xg GEMM: xg[t][d][col][b][jn*4+g] = X@Wih^T + bias ------
// 128x128 tile, BK=64, m97-style staging, 4 waves 2x2.
// 1D grid + supertile swizzle (4 bx x 8 by contiguous) so A-tiles
// (4x256KB) and B-tiles (8x256KB) stay cache-resident across reuse.
__global__ __launch_bounds__(256, 2) void xg_gemm(
    const u16* __restrict__ X, int Kx, int Kfull, const u16* __restrict__ Wc,
    const float* __restrict__ bsumL, u16* __restrict__ xg) {
  __shared__ __align__(16) char lds[32768];  // A 16K + B 16K
  const int tid = threadIdx.x;
  const int lane = tid & 63, wv = tid >> 6;
  const int wm = wv & 1, wn = wv >> 1;
  const int col = lane & 15, quad = lane >> 4;
  const int s = blockIdx.x >> 5, w = blockIdx.x & 31;
  const int bx = (s % 40) * 4 + (w & 3);
  const int by = (s / 40) * 8 + (w >> 2);
  const int tb0 = bx * 128;
  const int d = by >> 4, colb = by & 15, j0 = colb * 32;

  f32x4 zero = {0.f, 0.f, 0.f, 0.f};
  f32x4 acc[4][4];
#pragma unroll
  for (int i = 0; i < 4; ++i)
#pragma unroll
    for (int j = 0; j < 4; ++j) acc[i][j] = zero;

  const int iters = Kx >> 6;
  for (int it = 0; it < iters; ++it) {
    int k0 = it << 6;
#pragma unroll
    for (int p = 0; p < 8; ++p) {
      int c = p * 256 + tid;  // [0,2048)
      const u16* gsrc;
      if (c < 1024) {  // A rows 0..127
        int r = c >> 3, sl = c & 7;
        int kk = k0 + ((sl * 8) ^ ((r & 7) << 3));
        gsrc = X + (long)(tb0 + r) * Kx + kk;
      } else {
        int cb = c - 1024;
        int r = cb >> 3, sl = cb & 7;
        int kk = k0 + ((sl * 8) ^ ((r & 7) << 3));
        int grow = (r >> 5) * 512 + j0 + (r & 31);
        gsrc = Wc + ((long)d * G4 + grow) * Kfull + kk;
      }
      __builtin_amdgcn_global_load_lds(
          (const __attribute__((address_space(1))) void*)(const void*)gsrc,
          (__attribute__((address_space(3))) void*)(lds + p * 4096 + wv * 1024),
          16, 0, 0);
    }
    __syncthreads();
    const u16* As = (const u16*)lds;
    const u16* Bs = (const u16*)(lds + 16384);
#pragma unroll
    for (int ks = 0; ks < 2; ++ks) {
      short8 afr[4], bfr[4];
#pragma unroll
      for (int mf = 0; mf < 4; ++mf) {
        int rm = wm * 64 + mf * 16 + col;
        int sl = (ks * 32 + quad * 8) ^ ((rm & 7) << 3);
        afr[mf] = *(const short8*)(As + rm * 64 + sl);
      }
#pragma unroll
      for (int nf = 0; nf < 4; ++nf) {
        int br = wn * 64 + nf * 16 + col;
        int sl = (ks * 32 + quad * 8) ^ ((br & 7) << 3);
        bfr[nf] = *(const short8*)(Bs + br * 64 + sl);
      }
#pragma unroll
      for (int mf = 0; mf < 4; ++mf)
#pragma unroll
        for (int nf = 0; nf < 4; ++nf)
          acc[mf][nf] = __builtin_amdgcn_mfma_f32_16x16x32_bf16(
              afr[mf], bfr[nf], acc[mf][nf], 0, 0, 0);
    }
    __syncthreads();
  }

  float bias[4];
#pragma unroll
  for (int nf = 0; nf < 4; ++nf) {
    int n = wn * 64 + nf * 16 + col;
    bias[nf] = bsumL[d * G4 + (n >> 5) * 512 + j0 + (n & 31)];
  }
#pragma unroll
  for (int mf = 0; mf < 4; ++mf)
#pragma unroll
    for (int nf = 0; nf < 4; ++nf) {
      int n = wn * 64 + nf * 16 + col;
      int g = n >> 5, jn = n & 31;
#pragma unroll
      for (int r = 0; r < 4; ++r) {
        int m = wm * 64 + mf * 16 + quad * 4 + r;
        int tb = tb0 + m, t = tb >> 9, b = tb & 511;
        long oi = ((((long)t * 2 + d) * 16 + colb) * 512 + b) * 128 + jn * 4 + g;
        xg[oi] = f2bf(acc[mf][nf][r] + bias[nf]);
      }
    }
}

// ---------------- persistent bidirectional LSTM recurrence ----------------
// R14 = R8/R0 verbatim except the K-loop staging and store deferral.
// R8's K-loop exposed ~4 LLC stage latencies per step (stage(it+1) issued,
// ~0.2us compute, then __syncthreads drains vmcnt -> ~0.8us exposed, x4).
// R14 stages h in 2 x 32KB halves (64 rows x 256 k), single-buffered:
//   stageH(0); bar; compute k<256 (no inner barriers, all resident);
//   bar; stageH(1); bar; compute k>=256.
// -> 2 exposed waits instead of 4. LDS = Whh 128K + stage 32K = 160 KiB.
// Also: h0cat/output HBM stores deferred until after the flag (values in
// regs), so the rendezvous vmcnt(0) drain only waits on 2KB LLC stores.
// Everything else (geometry, rendezvous, layouts, xg_gemm) is the R0/R8
// verified-good 1000us config.
__global__ __launch_bounds__(256, 1) void lstm_pers(
    const u16* __restrict__ xg, const u16* __restrict__ Wc, int Kfull, int Kx,
    u16* __restrict__ hbuf, u16* __restrict__ h0cat, void* __restrict__ outp,
    const int* __restrict__ qlen, const int* __restrict__ flag,
    unsigned int* bar, int layer) {
  __shared__ __align__(16) char lds[163840];  // [Whh 128K][h-stage 32K]
  const int tid = threadIdx.x;
  const int lane = tid & 63, wv = tid >> 6;
  const int wm = wv & 1, wn = wv >> 1;
  const int col = lane & 15, quad = lane >> 4;
  const int l = blockIdx.x;
  const int colid = l & 31, mi = l >> 5;
  const int colb = colid & 15, j0 = colb * 32, d = colid >> 4;
  const int m0 = mi * 64;
  const int gid = l >> 4;  // == mi*2 + d (16 groups of 16 blocks)

  // ---- preload Whh slice into LDS: rows r=g*32+jn, [128][512] swizzled ----
#pragma unroll
  for (int p = 0; p < 32; ++p) {
    int c = p * 256 + tid;
    int row = c >> 6, rem = c & 63;
    int kc = rem >> 3, sl = rem & 7;
    int grow = (row >> 5) * 512 + j0 + (row & 31);
    int gk = Kx + kc * 64 + ((sl * 8) ^ ((row & 7) << 3));
    const u16* gsrc = Wc + ((long)d * G4 + grow) * Kfull + gk;
    __builtin_amdgcn_global_load_lds(
        (const __attribute__((address_space(1))) void*)(const void*)gsrc,
        (__attribute__((address_space(3))) void*)(lds + p * 4096 + wv * 1024),
        16, 0, 0);
  }
  const u16* Bs = (const u16*)lds;
  char* hstg = lds + 131072;  // 32 KB single-buffer h stage
  u16* hLDS = (u16*)hstg;     // epilogue pack [64 m][32 jn] aliases stage

  float creg[2][4];
#pragma unroll
  for (int i = 0; i < 2; ++i)
#pragma unroll
    for (int r = 0; r < 4; ++r) creg[i][r] = 0.f;
  const int isbf = *flag;
  f32x4 zero = {0.f, 0.f, 0.f, 0.f};

  __syncthreads();  // Whh resident

#pragma unroll 1
  for (int t = 0; t < NW; ++t) {
    const int tq = d ? (NW - 1 - t) : t;

    // xg prefetch: thread cell (m = wm*32+mf*16+quad*4+r, j = wn*16+col)
    ushort4 xgv[2][4];
    const u16* xgt = xg + ((((long)tq * 2 + d) * 16 + colb) * 512 + m0) * 128;
#pragma unroll
    for (int mf = 0; mf < 2; ++mf)
#pragma unroll
      for (int r = 0; r < 4; ++r) {
        int m = wm * 32 + mf * 16 + quad * 4 + r;
        xgv[mf][r] = *(const ushort4*)(xgt + m * 128 + (wn * 16 + col) * 4);
      }

    f32x4 acc[2][4];  // [mf][gate]
#pragma unroll
    for (int i = 0; i < 2; ++i)
#pragma unroll
      for (int j = 0; j < 4; ++j) acc[i][j] = zero;

    if (t > 0) {
      const u16* hp =
          hbuf + ((t - 1) & 1) * (2L * NB * NH) + ((long)d * NB + m0) * NH;
      // stage one k-half: 64 rows x 256 k = 32 KB via LDS-DMA, SC1 (LLC)
      auto stageH = [&](int half) {
#pragma unroll
        for (int p = 0; p < 8; ++p) {
          int c = p * 256 + tid;  // [0,2048)
          int row = c >> 5, slot = c & 31;
          int kk = half * 256 + (slot >> 3) * 64 +
                   (((slot & 7) * 8) ^ ((row & 7) << 3));
          const u16* gsrc = hp + (long)row * NH + kk;
          __builtin_amdgcn_global_load_lds(
              (const __attribute__((address_space(1))) void*)(const void*)gsrc,
              (__attribute__((address_space(3))) void*)(hstg + p * 4096 +
                                                        wv * 1024),
              16, 0, 16 /* SC1: agent-coherent read from LLC */);
        }
      };
      const u16* As = (const u16*)hstg;
#pragma unroll 1
      for (int half = 0; half < 2; ++half) {
        stageH(half);
        __syncthreads();  // half resident (exposed LLC wait, 2x per step)
#pragma unroll
        for (int ks = 0; ks < 8; ++ks) {
          const int ksub = ks * 32 + quad * 8;  // [0,256)
          short8 afr[2];
#pragma unroll
          for (int mf = 0; mf < 2; ++mf) {
            int rm = wm * 32 + mf * 16 + col;
            afr[mf] = *(const short8*)(As + rm * 256 + (ksub & ~63) +
                                       ((ksub & 63) ^ ((rm & 7) << 3)));
          }
          const int kc = half * 256 + ksub;
#pragma unroll
          for (int g = 0; g < 4; ++g) {
            int br = g * 32 + wn * 16 + col;
            int slb = (kc & 63) ^ ((br & 7) << 3);
            short8 bfr = *(const short8*)(Bs + br * 512 + (kc & ~63) + slb);
#pragma unroll
            for (int mf = 0; mf < 2; ++mf)
              acc[mf][g] = __builtin_amdgcn_mfma_f32_16x16x32_bf16(
                  afr[mf], bfr, acc[mf][g], 0, 0, 0);
          }
        }
        __syncthreads();  // all reads of this half done (re-stage / pack safe)
      }
    }

    // ---- register-only cell update; pack h into 4 KB LDS ----
#pragma unroll
    for (int mf = 0; mf < 2; ++mf)
#pragma unroll
      for (int r = 0; r < 4; ++r) {
        int m = wm * 32 + mf * 16 + quad * 4 + r;
        const u16* xv = (const u16*)&xgv[mf][r];
        float gi = acc[mf][0][r] + bf2f(xv[0]);
        float gf = acc[mf][1][r] + bf2f(xv[1]);
        float gg = acc[mf][2][r] + bf2f(xv[2]);
        float go = acc[mf][3][r] + bf2f(xv[3]);
        float si = sigm(gi);
        float sf = sigm(gf);
        float so = sigm(go);
        float cn = sf * creg[mf][r] + si * fast_tanh(gg);
        float h = so * fast_tanh(cn);
        creg[mf][r] = cn;
        hLDS[m * 32 + wn * 16 + col] = f2bf(h);
        // fp32 output path: store full-precision h directly (rare rows)
        if (layer == 1 && !isbf) {
          int bg = m0 + m;
          if (qlen[bg] - 1 == tq)
            ((float*)outp)[(long)bg * (2 * NH) + d * NH + j0 + wn * 16 + col] =
                h;
        }
      }
    __syncthreads();

    // ---- hbuf (LLC) stores; keep values in regs for deferred HBM stores --
    u16* hnxt = hbuf + (t & 1) * (2L * NB * NH);
    u32 hw[4];
    int bgp[4], jgp[4];
#pragma unroll
    for (int p = 0; p < 4; ++p) {
      int c = p * 256 + tid;  // [0,1024) pairs
      int m = c >> 4, pr = c & 15;
      hw[p] = ((const u32*)hLDS)[m * 16 + pr];
      bgp[p] = m0 + m;
      jgp[p] = j0 + pr * 2;
      __hip_atomic_store(
          (u32*)(hnxt + ((long)d * NB + bgp[p]) * NH + jgp[p]), hw[p],
          __ATOMIC_RELAXED, __HIP_MEMORY_SCOPE_AGENT);
    }

    // ---- group barrier (16 blocks sharing (mi,d)), relaxed agent atomics --
    if (t < NW - 1) {
      __syncthreads();  // drains vmcnt: hbuf stores visible at LLC
      if (tid == 0) {
        u32* cnt = &bar[gid * 64];
        u32* flg = &bar[1024 + gid * 64];
        unsigned old = __hip_atomic_fetch_add(cnt, 1u, __ATOMIC_RELAXED,
                                              __HIP_MEMORY_SCOPE_AGENT);
        if (old == 16u * (t + 1) - 1u)
          __hip_atomic_store(flg, (unsigned)(t + 1), __ATOMIC_RELAXED,
                             __HIP_MEMORY_SCOPE_AGENT);
        else
          while (__hip_atomic_load(flg, __ATOMIC_RELAXED,
                                   __HIP_MEMORY_SCOPE_AGENT) <
                 (unsigned)(t + 1))
            __builtin_amdgcn_s_sleep(1);
      }
      __syncthreads();
    }

    // ---- deferred HBM stores (off the rendezvous drain path) ----
#pragma unroll
    for (int p = 0; p < 4; ++p) {
      if (layer == 0) {
        *(u32*)(h0cat + ((long)tq * NB + bgp[p]) * (2 * NH) + d * NH +
                jgp[p]) = hw[p];
      } else if (isbf && qlen[bgp[p]] - 1 == tq) {
        *(u32*)((u16*)outp + (long)bgp[p] * (2 * NH) + d * NH + jgp[p]) =
            hw[p];
      }
    }
  }
}

extern "C" void kernel_launch(void* const* d_in, const int* in_sizes, int n_in,
                              void* d_out, int out_size, void* d_ws,
                              size_t ws_size, hipStream_t stream) {
  const int* qv = (const int*)d_in[0];
  const int* ql = (const int*)d_in[1];
  const void* lookup = d_in[2];
  const void* wih0 = d_in[3];
  const void* whh0 = d_in[4];
  const void* b0 = d_in[5];
  const void* wih1 = d_in[6];
  const void* whh1 = d_in[7];
  const void* b1 = d_in[8];

  char* ws = (char*)d_ws;
  size_t off = 0;
  int* flag = (int*)ws;                 off += 256;
  unsigned int* bar = (unsigned int*)(ws + off); off += 8192;
  float* bsum = (float*)(ws + off);     off += 2L * 2 * G4 * 4;        // 32 KB
  u16* Wc0 = (u16*)(ws + off);          off += 2L * G4 * 1024 * 2;     // 8 MB
  u16* Wc1 = (u16*)(ws + off);          off += 2L * G4 * 1536 * 2;     // 12 MB
  u16* hbuf = (u16*)(ws + off);         off += 2L * 2 * NB * NH * 2;   // 2 MB
  u16* h0cat = (u16*)(ws + off);        off += (size_t)NW * NB * 2 * NH * 2; // 40 MB
  u16* emb = (u16*)(ws + off);          off += (size_t)NW * NB * NE * 2;     // 20 MB
  u16* xg = (u16*)(ws + off);           off += (size_t)NW * 2 * 16 * 512 * 128 * 2; // 168 MB
  u16* tableT = h0cat;  // tableT (12.3 MB) aliases h0cat: dead before layer0

  detect_kernel<<<1, 64, 0, stream>>>((const u16*)lookup, flag);
  table_kernel<<<dim3(188, 8), dim3(64, 4), 0, stream>>>(lookup, flag, tableT);
  {
    long total = 2L * G4 * 1024 + 2L * G4 * 1536 + 2L * 2 * G4;
    int blocks = (int)((total + 255) / 256);
    pack_kernel<<<blocks, 256, 0, stream>>>(wih0, whh0, b0, wih1, whh1, b1,
                                            flag, Wc0, Wc1, bsum);
  }
  embed_kernel<<<NW * NB / 4, 256, 0, stream>>>(qv, tableT, emb);

  // layer 0
  xg_gemm<<<5120, 256, 0, stream>>>(emb, 512, 1024, Wc0, bsum, xg);
  zero_bar<<<8, 256, 0, stream>>>(bar);
  lstm_pers<<<256, 256, 0, stream>>>(xg, Wc0, 1024, 512, hbuf, h0cat, d_out,
                                     ql, flag, bar, 0);
  // layer 1
  xg_gemm<<<5120, 256, 0, stream>>>(h0cat, 1024, 1536, Wc1, bsum + 2 * G4, xg);
  zero_bar<<<8, 256, 0, stream>>>(bar);
  lstm_pers<<<256, 256, 0, stream>>>(xg, Wc1, 1536, 1024, hbuf, h0cat, d_out,
                                     ql, flag, bar, 1);
}

// Round 7
// 853.575 us; speedup vs baseline: 1.4002x; 1.1121x over previous
//
#include <hip/hip_runtime.h>
#include <hip/hip_bf16.h>
#include <stdint.h>

#define NB 512
#define NW 40
#define NE 512
#define NH 512
#define NV 12000
#define G4 2048

typedef unsigned short u16;
typedef unsigned int u32;
typedef unsigned long long u64;
typedef __attribute__((ext_vector_type(8))) short short8;
typedef __attribute__((ext_vector_type(4))) float f32x4;

__device__ __forceinline__ unsigned short f2bf(float f) {
  unsigned int u = __float_as_uint(f);
  u += 0x7FFF + ((u >> 16) & 1);
  return (unsigned short)(u >> 16);
}
__device__ __forceinline__ float bf2f(unsigned short b) {
  return __uint_as_float(((unsigned int)b) << 16);
}
__device__ __forceinline__ float loadIn(const void* p, long i, int bf) {
  return bf ? bf2f(((const u16*)p)[i]) : ((const float*)p)[i];
}
// exp-based tanh: |err| ~1e-7 abs, saturates cleanly (exp->inf => 1).
__device__ __forceinline__ float fast_tanh(float x) {
  float ax = __builtin_fabsf(x);
  float t = 1.f - 2.f * __builtin_amdgcn_rcpf(__expf(ax + ax) + 1.f);
  return __builtin_copysignf(t, x);
}
__device__ __forceinline__ float sigm(float x) {
  return __builtin_amdgcn_rcpf(1.f + __expf(-x));
}

// ---------------- dtype detector ----------------
__global__ void detect_kernel(const u16* p, int* flag) {
  __shared__ int cnt;
  int i = threadIdx.x;
  if (i == 0) cnt = 0;
  __syncthreads();
  unsigned short u = p[2 * (i * 1001)];
  int e = (u >> 7) & 0xFF;
  if (e >= 100 && e <= 126) atomicAdd(&cnt, 1);
  __syncthreads();
  if (i == 0) *flag = (cnt >= 32) ? 1 : 0;
}

// ---------------- tableT = bf16(tanh(lookup_W^T)), (V, E) ----------------
__global__ void table_kernel(const void* lookup, const int* flag, u16* tableT) {
  __shared__ float tile[64][65];
  int bf = *flag;
  int v0 = blockIdx.x * 64, e0 = blockIdx.y * 64;
  int tx = threadIdx.x, ty = threadIdx.y;  // (64,4)
#pragma unroll
  for (int r = 0; r < 16; ++r) {
    int e = r * 4 + ty, v = tx;
    if (v0 + v < NV)
      tile[e][v] = tanhf(loadIn(lookup, (long)(e0 + e) * NV + v0 + v, bf));
  }
  __syncthreads();
#pragma unroll
  for (int r = 0; r < 16; ++r) {
    int v = r * 4 + ty, e = tx;
    if (v0 + v < NV)
      tableT[(long)(v0 + v) * NE + e0 + e] = f2bf(tile[e][v]);
  }
}

// ---------------- pack weights: Wc[d] rows = [wih | whh], bf16 ------------
// R15: also writes G[0] = bias row (layer0), order [d][colb][jn*4+g].
__global__ void pack_kernel(const void* wih0, const void* whh0, const void* b0,
                            const void* wih1, const void* whh1, const void* b1,
                            const int* flag, u16* Wc0, u16* Wc1, float* bsum,
                            u16* G) {
  const long N0 = 2L * G4 * 1024, N1 = 2L * G4 * 1536;
  const long NB2 = 2L * 2 * G4;
  long idx = (long)blockIdx.x * 256 + threadIdx.x;
  int bf = *flag;
  if (idx < N0) {
    int d = (int)(idx / (G4 * 1024));
    int rem = (int)(idx % (long)(G4 * 1024));
    int g = rem / 1024, k = rem % 1024;
    float v = (k < 512) ? loadIn(wih0, ((long)d * G4 + g) * 512 + k, bf)
                        : loadIn(whh0, ((long)d * G4 + g) * 512 + (k - 512), bf);
    Wc0[idx] = f2bf(v);
  } else if (idx < N0 + N1) {
    long i2 = idx - N0;
    int d = (int)(i2 / (G4 * 1536));
    int rem = (int)(i2 % (long)(G4 * 1536));
    int g = rem / 1536, k = rem % 1536;
    float v = (k < 1024) ? loadIn(wih1, ((long)d * G4 + g) * 1024 + k, bf)
                         : loadIn(whh1, ((long)d * G4 + g) * 512 + (k - 1024), bf);
    Wc1[i2] = f2bf(v);
  } else if (idx < N0 + N1 + NB2) {
    long i3 = idx - N0 - N1;  // [layer][d][g]
    int layer = (int)(i3 / (2 * G4));
    int d = (int)((i3 / G4) & 1);
    int g = (int)(i3 % G4);
    const void* bb = layer ? b1 : b0;
    float v = loadIn(bb, (long)d * 2 * G4 + g, bf) +
              loadIn(bb, (long)d * 2 * G4 + G4 + g, bf);
    bsum[i3] = v;
  } else if (idx < N0 + N1 + NB2 + 4096) {
    int n = (int)(idx - N0 - N1 - NB2);  // [0,4096): G[0] bias row
    int d = n >> 11, loc = n & 2047;
    int colb = loc >> 7, rr = loc & 127;
    int jn = rr >> 2, g = rr & 3;
    int grow = g * 512 + colb * 32 + jn;
    float v = loadIn(b0, (long)d * 2 * G4 + grow, bf) +
              loadIn(b0, (long)d * 2 * G4 + G4 + grow, bf);
    G[n] = f2bf(v);
  }
}

// ---------------- zero the barrier (8 KB) ----------------
__global__ void zero_bar(unsigned int* bar) {
  bar[blockIdx.x * 256 + threadIdx.x] = 0u;
}

// ---------------- G GEMM: G[1+v] = tableT[v] @ Wih0^T + bias --------------
// R15: layer-0 x-gates depend on the token only through q (12001 distinct
// values) -- compute per-VOCAB-ROW gates once (50 GF) instead of per-token
// (86 GF), and let the lstm gather G[q] directly (no xg materialization).
// Same 128x128 m97-style tile as xg_gemm; A = tableT rows (M=12032 incl.
// pad, garbage pad rows only pollute unstored C rows); grid bx-major so the
// A-tile is L2-resident across its 32 consecutive by-blocks.
// G row layout: [d 2][colb 16][jn*4+g 128] (matches lstm xgv gather).
__global__ __launch_bounds__(256, 3) void g_gemm(
    const u16* __restrict__ tableT, const u16* __restrict__ Wc,
    const float* __restrict__ bsumL, u16* __restrict__ G) {
  __shared__ __align__(16) char lds[32768];  // A 16K + B 16K
  const int tid = threadIdx.x;
  const int lane = tid & 63, wv = tid >> 6;
  const int wm = wv & 1, wn = wv >> 1;
  const int col = lane & 15, quad = lane >> 4;
  const int bx = blockIdx.x >> 5;  // 0..93
  const int by = blockIdx.x & 31;
  const int tb0 = bx * 128;  // vocab row base
  const int d = by >> 4, colb = by & 15, j0 = colb * 32;

  f32x4 zero = {0.f, 0.f, 0.f, 0.f};
  f32x4 acc[4][4];
#pragma unroll
  for (int i = 0; i < 4; ++i)
#pragma unroll
    for (int j = 0; j < 4; ++j) acc[i][j] = zero;

  for (int it = 0; it < 8; ++it) {
    int k0 = it << 6;
#pragma unroll
    for (int p = 0; p < 8; ++p) {
      int c = p * 256 + tid;  // [0,2048)
      const u16* gsrc;
      if (c < 1024) {  // A rows (vocab)
        int r = c >> 3, sl = c & 7;
        int kk = k0 + ((sl * 8) ^ ((r & 7) << 3));
        gsrc = tableT + (long)(tb0 + r) * 512 + kk;
      } else {
        int cb = c - 1024;
        int r = cb >> 3, sl = cb & 7;
        int kk = k0 + ((sl * 8) ^ ((r & 7) << 3));
        int grow = (r >> 5) * 512 + j0 + (r & 31);
        gsrc = Wc + ((long)d * G4 + grow) * 1024 + kk;  // wih part (k<512)
      }
      __builtin_amdgcn_global_load_lds(
          (const __attribute__((address_space(1))) void*)(const void*)gsrc,
          (__attribute__((address_space(3))) void*)(lds + p * 4096 + wv * 1024),
          16, 0, 0);
    }
    __syncthreads();
    const u16* As = (const u16*)lds;
    const u16* Bs = (const u16*)(lds + 16384);
#pragma unroll
    for (int ks = 0; ks < 2; ++ks) {
      short8 afr[4], bfr[4];
#pragma unroll
      for (int mf = 0; mf < 4; ++mf) {
        int rm = wm * 64 + mf * 16 + col;
        int sl = (ks * 32 + quad * 8) ^ ((rm & 7) << 3);
        afr[mf] = *(const short8*)(As + rm * 64 + sl);
      }
#pragma unroll
      for (int nf = 0; nf < 4; ++nf) {
        int br = wn * 64 + nf * 16 + col;
        int sl = (ks * 32 + quad * 8) ^ ((br & 7) << 3);
        bfr[nf] = *(const short8*)(Bs + br * 64 + sl);
      }
#pragma unroll
      for (int mf = 0; mf < 4; ++mf)
#pragma unroll
        for (int nf = 0; nf < 4; ++nf)
          acc[mf][nf] = __builtin_amdgcn_mfma_f32_16x16x32_bf16(
              afr[mf], bfr[nf], acc[mf][nf], 0, 0, 0);
    }
    __syncthreads();
  }

  float bias[4];
#pragma unroll
  for (int nf = 0; nf < 4; ++nf) {
    int n = wn * 64 + nf * 16 + col;
    bias[nf] = bsumL[d * G4 + (n >> 5) * 512 + j0 + (n & 31)];
  }
#pragma unroll
  for (int mf = 0; mf < 4; ++mf)
#pragma unroll
    for (int nf = 0; nf < 4; ++nf) {
      int n = wn * 64 + nf * 16 + col;
      int g = n >> 5, jn = n & 31;
#pragma unroll
      for (int r = 0; r < 4; ++r) {
        int m = wm * 64 + mf * 16 + quad * 4 + r;
        int v = tb0 + m;
        if (v < NV)
          G[(long)(v + 1) * 4096 + ((d * 16 + colb) << 7) + jn * 4 + g] =
              f2bf(acc[mf][nf][r] + bias[nf]);
      }
    }
}

// ---------------- xg GEMM (layer 1): xg[t][d][col][b][jn*4+g] -------------
// 128x128 tile, BK=64, m97-style staging, 4 waves 2x2; supertile swizzle.
// R15: __launch_bounds__(256,3) -- cap VGPR at ~170 so 3 blocks/CU
// co-reside and cover the barrier drain (m97-structure stall).
__global__ __launch_bounds__(256, 3) void xg_gemm(
    const u16* __restrict__ X, int Kx, int Kfull, const u16* __restrict__ Wc,
    const float* __restrict__ bsumL, u16* __restrict__ xg) {
  __shared__ __align__(16) char lds[32768];  // A 16K + B 16K
  const int tid = threadIdx.x;
  const int lane = tid & 63, wv = tid >> 6;
  const int wm = wv & 1, wn = wv >> 1;
  const int col = lane & 15, quad = lane >> 4;
  const int s = blockIdx.x >> 5, w = blockIdx.x & 31;
  const int bx = (s % 40) * 4 + (w & 3);
  const int by = (s / 40) * 8 + (w >> 2);
  const int tb0 = bx * 128;
  const int d = by >> 4, colb = by & 15, j0 = colb * 32;

  f32x4 zero = {0.f, 0.f, 0.f, 0.f};
  f32x4 acc[4][4];
#pragma unroll
  for (int i = 0; i < 4; ++i)
#pragma unroll
    for (int j = 0; j < 4; ++j) acc[i][j] = zero;

  const int iters = Kx >> 6;
  for (int it = 0; it < iters; ++it) {
    int k0 = it << 6;
#pragma unroll
    for (int p = 0; p < 8; ++p) {
      int c = p * 256 + tid;  // [0,2048)
      const u16* gsrc;
      if (c < 1024) {  // A rows 0..127
        int r = c >> 3, sl = c & 7;
        int kk = k0 + ((sl * 8) ^ ((r & 7) << 3));
        gsrc = X + (long)(tb0 + r) * Kx + kk;
      } else {
        int cb = c - 1024;
        int r = cb >> 3, sl = cb & 7;
        int kk = k0 + ((sl * 8) ^ ((r & 7) << 3));
        int grow = (r >> 5) * 512 + j0 + (r & 31);
        gsrc = Wc + ((long)d * G4 + grow) * Kfull + kk;
      }
      __builtin_amdgcn_global_load_lds(
          (const __attribute__((address_space(1))) void*)(const void*)gsrc,
          (__attribute__((address_space(3))) void*)(lds + p * 4096 + wv * 1024),
          16, 0, 0);
    }
    __syncthreads();
    const u16* As = (const u16*)lds;
    const u16* Bs = (const u16*)(lds + 16384);
#pragma unroll
    for (int ks = 0; ks < 2; ++ks) {
      short8 afr[4], bfr[4];
#pragma unroll
      for (int mf = 0; mf < 4; ++mf) {
        int rm = wm * 64 + mf * 16 + col;
        int sl = (ks * 32 + quad * 8) ^ ((rm & 7) << 3);
        afr[mf] = *(const short8*)(As + rm * 64 + sl);
      }
#pragma unroll
      for (int nf = 0; nf < 4; ++nf) {
        int br = wn * 64 + nf * 16 + col;
        int sl = (ks * 32 + quad * 8) ^ ((br & 7) << 3);
        bfr[nf] = *(const short8*)(Bs + br * 64 + sl);
      }
#pragma unroll
      for (int mf = 0; mf < 4; ++mf)
#pragma unroll
        for (int nf = 0; nf < 4; ++nf)
          acc[mf][nf] = __builtin_amdgcn_mfma_f32_16x16x32_bf16(
              afr[mf], bfr[nf], acc[mf][nf], 0, 0, 0);
    }
    __syncthreads();
  }

  float bias[4];
#pragma unroll
  for (int nf = 0; nf < 4; ++nf) {
    int n = wn * 64 + nf * 16 + col;
    bias[nf] = bsumL[d * G4 + (n >> 5) * 512 + j0 + (n & 31)];
  }
#pragma unroll
  for (int mf = 0; mf < 4; ++mf)
#pragma unroll
    for (int nf = 0; nf < 4; ++nf) {
      int n = wn * 64 + nf * 16 + col;
      int g = n >> 5, jn = n & 31;
#pragma unroll
      for (int r = 0; r < 4; ++r) {
        int m = wm * 64 + mf * 16 + quad * 4 + r;
        int tb = tb0 + m, t = tb >> 9, b = tb & 511;
        long oi = ((((long)t * 2 + d) * 16 + colb) * 512 + b) * 128 + jn * 4 + g;
        xg[oi] = f2bf(acc[mf][nf][r] + bias[nf]);
      }
    }
}

// ---------------- persistent bidirectional LSTM recurrence ----------------
// R15 = R14's verified structure (2x32KB half staging, deferred HBM stores)
// with two changes:
//  * layer 0 reads x-gates by GATHER from G[qv[b,tq]] (LLC-resident 98 MB)
//    instead of a materialized xg stream: qv + G loads issued at step top,
//    consumed ~4us later after the poll -> latency hidden. Layer 1 keeps
//    the xg path.
//  * rendezvous: per-writer flag slots (no 16-way serialized fetch_add on
//    one LLC line); the wait moved to just-before-staging so next-step
//    xgv/qv prefetch issues ahead of it. Same 2-slot hbuf safety induction
//    as R10/R11: block X stores h(t) only after passing poll(>=t), which
//    requires all blocks signaled end-of-step t-1, hence finished reading
//    h(t-2) from the slot being overwritten.
__global__ __launch_bounds__(256, 1) void lstm_pers(
    const u16* __restrict__ xg, const int* __restrict__ qv,
    const u16* __restrict__ Wc, int Kfull, int Kx, u16* __restrict__ hbuf,
    u16* __restrict__ h0cat, void* __restrict__ outp,
    const int* __restrict__ qlen, const int* __restrict__ flag,
    unsigned int* bar, int layer) {
  __shared__ __align__(16) char lds[163840];  // [Whh 128K][h-stage 32K]
  const int tid = threadIdx.x;
  const int lane = tid & 63, wv = tid >> 6;
  const int wm = wv & 1, wn = wv >> 1;
  const int col = lane & 15, quad = lane >> 4;
  const int l = blockIdx.x;
  const int colid = l & 31, mi = l >> 5;
  const int colb = colid & 15, j0 = colb * 32, d = colid >> 4;
  const int m0 = mi * 64;
  const int gid = l >> 4;  // == mi*2 + d (16 groups of 16 blocks)

  // ---- preload Whh slice into LDS: rows r=g*32+jn, [128][512] swizzled ----
#pragma unroll
  for (int p = 0; p < 32; ++p) {
    int c = p * 256 + tid;
    int row = c >> 6, rem = c & 63;
    int kc = rem >> 3, sl = rem & 7;
    int grow = (row >> 5) * 512 + j0 + (row & 31);
    int gk = Kx + kc * 64 + ((sl * 8) ^ ((row & 7) << 3));
    const u16* gsrc = Wc + ((long)d * G4 + grow) * Kfull + gk;
    __builtin_amdgcn_global_load_lds(
        (const __attribute__((address_space(1))) void*)(const void*)gsrc,
        (__attribute__((address_space(3))) void*)(lds + p * 4096 + wv * 1024),
        16, 0, 0);
  }
  const u16* Bs = (const u16*)lds;
  char* hstg = lds + 131072;  // 32 KB single-buffer h stage
  u16* hLDS = (u16*)hstg;     // epilogue pack [64 m][32 jn] aliases stage

  float creg[2][4];
#pragma unroll
  for (int i = 0; i < 2; ++i)
#pragma unroll
    for (int r = 0; r < 4; ++r) creg[i][r] = 0.f;
  const int isbf = *flag;
  f32x4 zero = {0.f, 0.f, 0.f, 0.f};

  __syncthreads();  // Whh resident

#pragma unroll 1
  for (int t = 0; t < NW; ++t) {
    const int tq = d ? (NW - 1 - t) : t;

    // x-gate prefetch (issued before the poll; ~4us of slack to use)
    ushort4 xgv[2][4];
    if (layer == 0) {
#pragma unroll
      for (int mf = 0; mf < 2; ++mf)
#pragma unroll
        for (int r = 0; r < 4; ++r) {
          int m = wm * 32 + mf * 16 + quad * 4 + r;
          int q = qv[(m0 + m) * NW + tq];
          xgv[mf][r] = *(const ushort4*)(xg + (long)q * 4096 +
                                         ((d * 16 + colb) << 7) +
                                         (wn * 16 + col) * 4);
        }
    } else {
      const u16* xgt =
          xg + ((((long)tq * 2 + d) * 16 + colb) * 512 + m0) * 128;
#pragma unroll
      for (int mf = 0; mf < 2; ++mf)
#pragma unroll
        for (int r = 0; r < 4; ++r) {
          int m = wm * 32 + mf * 16 + quad * 4 + r;
          xgv[mf][r] = *(const ushort4*)(xgt + m * 128 + (wn * 16 + col) * 4);
        }
    }

    f32x4 acc[2][4];  // [mf][gate]
#pragma unroll
    for (int i = 0; i < 2; ++i)
#pragma unroll
      for (int j = 0; j < 4; ++j) acc[i][j] = zero;

    if (t > 0) {
      // ---- per-writer slot poll: all 16 writers of (mi,d) signaled t ----
      if (wv == 0) {
        u32* sp = bar + gid * 16 + (lane & 15);
        while (__ballot((int)(__hip_atomic_load(sp, __ATOMIC_RELAXED,
                                                __HIP_MEMORY_SCOPE_AGENT) <
                              (u32)t)))
          __builtin_amdgcn_s_sleep(1);
      }
      __syncthreads();

      const u16* hp =
          hbuf + ((t - 1) & 1) * (2L * NB * NH) + ((long)d * NB + m0) * NH;
      // stage one k-half: 64 rows x 256 k = 32 KB via LDS-DMA, SC1 (LLC)
      auto stageH = [&](int half) {
#pragma unroll
        for (int p = 0; p < 8; ++p) {
          int c = p * 256 + tid;  // [0,2048)
          int row = c >> 5, slot = c & 31;
          int kk = half * 256 + (slot >> 3) * 64 +
                   (((slot & 7) * 8) ^ ((row & 7) << 3));
          const u16* gsrc = hp + (long)row * NH + kk;
          __builtin_amdgcn_global_load_lds(
              (const __attribute__((address_space(1))) void*)(const void*)gsrc,
              (__attribute__((address_space(3))) void*)(hstg + p * 4096 +
                                                        wv * 1024),
              16, 0, 16 /* SC1: agent-coherent read from LLC */);
        }
      };
      const u16* As = (const u16*)hstg;
#pragma unroll 1
      for (int half = 0; half < 2; ++half) {
        stageH(half);
        __syncthreads();  // half resident (exposed LLC wait, 2x per step)
#pragma unroll
        for (int ks = 0; ks < 8; ++ks) {
          const int ksub = ks * 32 + quad * 8;  // [0,256)
          short8 afr[2];
#pragma unroll
          for (int mf = 0; mf < 2; ++mf) {
            int rm = wm * 32 + mf * 16 + col;
            afr[mf] = *(const short8*)(As + rm * 256 + (ksub & ~63) +
                                       ((ksub & 63) ^ ((rm & 7) << 3)));
          }
          const int kc = half * 256 + ksub;
#pragma unroll
          for (int g = 0; g < 4; ++g) {
            int br = g * 32 + wn * 16 + col;
            int slb = (kc & 63) ^ ((br & 7) << 3);
            short8 bfr = *(const short8*)(Bs + br * 512 + (kc & ~63) + slb);
#pragma unroll
            for (int mf = 0; mf < 2; ++mf)
              acc[mf][g] = __builtin_amdgcn_mfma_f32_16x16x32_bf16(
                  afr[mf], bfr, acc[mf][g], 0, 0, 0);
          }
        }
        __syncthreads();  // all reads of this half done (re-stage / pack safe)
      }
    }

    // ---- register-only cell update; pack h into 4 KB LDS ----
#pragma unroll
    for (int mf = 0; mf < 2; ++mf)
#pragma unroll
      for (int r = 0; r < 4; ++r) {
        int m = wm * 32 + mf * 16 + quad * 4 + r;
        const u16* xv = (const u16*)&xgv[mf][r];
        float gi = acc[mf][0][r] + bf2f(xv[0]);
        float gf = acc[mf][1][r] + bf2f(xv[1]);
        float gg = acc[mf][2][r] + bf2f(xv[2]);
        float go = acc[mf][3][r] + bf2f(xv[3]);
        float si = sigm(gi);
        float sf = sigm(gf);
        float so = sigm(go);
        float cn = sf * creg[mf][r] + si * fast_tanh(gg);
        float h = so * fast_tanh(cn);
        creg[mf][r] = cn;
        hLDS[m * 32 + wn * 16 + col] = f2bf(h);
        // fp32 output path: store full-precision h directly (rare rows)
        if (layer == 1 && !isbf) {
          int bg = m0 + m;
          if (qlen[bg] - 1 == tq)
            ((float*)outp)[(long)bg * (2 * NH) + d * NH + j0 + wn * 16 + col] =
                h;
        }
      }
    __syncthreads();

    // ---- hbuf (LLC) stores; keep values in regs for deferred HBM stores --
    u16* hnxt = hbuf + (t & 1) * (2L * NB * NH);
    u32 hw[4];
    int bgp[4], jgp[4];
#pragma unroll
    for (int p = 0; p < 4; ++p) {
      int c = p * 256 + tid;  // [0,1024) pairs
      int m = c >> 4, pr = c & 15;
      hw[p] = ((const u32*)hLDS)[m * 16 + pr];
      bgp[p] = m0 + m;
      jgp[p] = j0 + pr * 2;
      __hip_atomic_store(
          (u32*)(hnxt + ((long)d * NB + bgp[p]) * NH + jgp[p]), hw[p],
          __ATOMIC_RELAXED, __HIP_MEMORY_SCOPE_AGENT);
    }

    // ---- drain hbuf stores, then signal own slot (non-blocking) ----
    if (t < NW - 1) {
      __syncthreads();  // drains vmcnt: hbuf stores visible at LLC
      if (tid == 0)
        __hip_atomic_store(bar + gid * 16 + colb, (u32)(t + 1),
                           __ATOMIC_RELAXED, __HIP_MEMORY_SCOPE_AGENT);
    }

    // ---- deferred HBM stores (off the rendezvous drain path) ----
#pragma unroll
    for (int p = 0; p < 4; ++p) {
      if (layer == 0) {
        *(u32*)(h0cat + ((long)tq * NB + bgp[p]) * (2 * NH) + d * NH +
                jgp[p]) = hw[p];
      } else if (isbf && qlen[bgp[p]] - 1 == tq) {
        *(u32*)((u16*)outp + (long)bgp[p] * (2 * NH) + d * NH + jgp[p]) =
            hw[p];
      }
    }
  }
}

extern "C" void kernel_launch(void* const* d_in, const int* in_sizes, int n_in,
                              void* d_out, int out_size, void* d_ws,
                              size_t ws_size, hipStream_t stream) {
  const int* qv = (const int*)d_in[0];
  const int* ql = (const int*)d_in[1];
  const void* lookup = d_in[2];
  const void* wih0 = d_in[3];
  const void* whh0 = d_in[4];
  const void* b0 = d_in[5];
  const void* wih1 = d_in[6];
  const void* whh1 = d_in[7];
  const void* b1 = d_in[8];

  char* ws = (char*)d_ws;
  size_t off = 0;
  int* flag = (int*)ws;                 off += 256;
  unsigned int* bar = (unsigned int*)(ws + off); off += 8192;
  float* bsum = (float*)(ws + off);     off += 2L * 2 * G4 * 4;        // 32 KB
  u16* Wc0 = (u16*)(ws + off);          off += 2L * G4 * 1024 * 2;     // 8 MB
  u16* Wc1 = (u16*)(ws + off);          off += 2L * G4 * 1536 * 2;     // 12 MB
  u16* hbuf = (u16*)(ws + off);         off += 2L * 2 * NB * NH * 2;   // 2 MB
  u16* h0cat = (u16*)(ws + off);        off += (size_t)NW * NB * 2 * NH * 2; // 40 MB
  u16* xg = (u16*)(ws + off);           off += (size_t)NW * 2 * 16 * 512 * 128 * 2; // 168 MB
  u16* tableT = h0cat;  // tableT (12.3 MB) aliases h0cat: dead before layer0
  u16* G = xg;  // G (98.3 MB) aliases xg: dead once layer-1 xg_gemm writes

  detect_kernel<<<1, 64, 0, stream>>>((const u16*)lookup, flag);
  table_kernel<<<dim3(188, 8), dim3(64, 4), 0, stream>>>(lookup, flag, tableT);
  {
    long total = 2L * G4 * 1024 + 2L * G4 * 1536 + 2L * 2 * G4 + 4096;
    int blocks = (int)((total + 255) / 256);
    pack_kernel<<<blocks, 256, 0, stream>>>(wih0, whh0, b0, wih1, whh1, b1,
                                            flag, Wc0, Wc1, bsum, G);
  }

  // layer 0: per-vocab gate GEMM + fused recurrence gather
  g_gemm<<<94 * 32, 256, 0, stream>>>(tableT, Wc0, bsum, G);
  zero_bar<<<8, 256, 0, stream>>>(bar);
  lstm_pers<<<256, 256, 0, stream>>>(G, qv, Wc0, 1024, 512, hbuf, h0cat,
                                     d_out, ql, flag, bar, 0);
  // layer 1
  xg_gemm<<<5120, 256, 0, stream>>>(h0cat, 1024, 1536, Wc1, bsum + 2 * G4, xg);
  zero_bar<<<8, 256, 0, stream>>>(bar);
  lstm_pers<<<256, 256, 0, stream>>>(xg, qv, Wc1, 1536, 1024, hbuf, h0cat,
                                     d_out, ql, flag, bar, 1);
}

// Round 8
// 832.545 us; speedup vs baseline: 1.4356x; 1.0253x over previous
//
#include <hip/hip_runtime.h>
#include <hip/hip_bf16.h>
#include <stdint.h>

#define NB 512
#define NW 40
#define NE 512
#define NH 512
#define NV 12000
#define G4 2048

typedef unsigned short u16;
typedef unsigned int u32;
typedef unsigned long long u64;
typedef __attribute__((ext_vector_type(8))) short short8;
typedef __attribute__((ext_vector_type(4))) float f32x4;

__device__ __forceinline__ unsigned short f2bf(float f) {
  unsigned int u = __float_as_uint(f);
  u += 0x7FFF + ((u >> 16) & 1);
  return (unsigned short)(u >> 16);
}
__device__ __forceinline__ float bf2f(unsigned short b) {
  return __uint_as_float(((unsigned int)b) << 16);
}
__device__ __forceinline__ float loadIn(const void* p, long i, int bf) {
  return bf ? bf2f(((const u16*)p)[i]) : ((const float*)p)[i];
}
// exp-based tanh: |err| ~1e-7 abs, saturates cleanly (exp->inf => 1).
__device__ __forceinline__ float fast_tanh(float x) {
  float ax = __builtin_fabsf(x);
  float t = 1.f - 2.f * __builtin_amdgcn_rcpf(__expf(ax + ax) + 1.f);
  return __builtin_copysignf(t, x);
}
__device__ __forceinline__ float sigm(float x) {
  return __builtin_amdgcn_rcpf(1.f + __expf(-x));
}

// ---------------- dtype detector ----------------
__global__ void detect_kernel(const u16* p, int* flag) {
  __shared__ int cnt;
  int i = threadIdx.x;
  if (i == 0) cnt = 0;
  __syncthreads();
  unsigned short u = p[2 * (i * 1001)];
  int e = (u >> 7) & 0xFF;
  if (e >= 100 && e <= 126) atomicAdd(&cnt, 1);
  __syncthreads();
  if (i == 0) *flag = (cnt >= 32) ? 1 : 0;
}

// ---------------- tableT = bf16(tanh(lookup_W^T)), (V, E) ----------------
__global__ void table_kernel(const void* lookup, const int* flag, u16* tableT) {
  __shared__ float tile[64][65];
  int bf = *flag;
  int v0 = blockIdx.x * 64, e0 = blockIdx.y * 64;
  int tx = threadIdx.x, ty = threadIdx.y;  // (64,4)
#pragma unroll
  for (int r = 0; r < 16; ++r) {
    int e = r * 4 + ty, v = tx;
    if (v0 + v < NV)
      tile[e][v] = tanhf(loadIn(lookup, (long)(e0 + e) * NV + v0 + v, bf));
  }
  __syncthreads();
#pragma unroll
  for (int r = 0; r < 16; ++r) {
    int v = r * 4 + ty, e = tx;
    if (v0 + v < NV)
      tableT[(long)(v0 + v) * NE + e0 + e] = f2bf(tile[e][v]);
  }
}

// ---------------- pack weights: Wc[d] rows = [wih | whh], bf16 ------------
// Also writes G[0] = bias row (layer0), order [d][colb][jn*4+g].
__global__ void pack_kernel(const void* wih0, const void* whh0, const void* b0,
                            const void* wih1, const void* whh1, const void* b1,
                            const int* flag, u16* Wc0, u16* Wc1, float* bsum,
                            u16* G) {
  const long N0 = 2L * G4 * 1024, N1 = 2L * G4 * 1536;
  const long NB2 = 2L * 2 * G4;
  long idx = (long)blockIdx.x * 256 + threadIdx.x;
  int bf = *flag;
  if (idx < N0) {
    int d = (int)(idx / (G4 * 1024));
    int rem = (int)(idx % (long)(G4 * 1024));
    int g = rem / 1024, k = rem % 1024;
    float v = (k < 512) ? loadIn(wih0, ((long)d * G4 + g) * 512 + k, bf)
                        : loadIn(whh0, ((long)d * G4 + g) * 512 + (k - 512), bf);
    Wc0[idx] = f2bf(v);
  } else if (idx < N0 + N1) {
    long i2 = idx - N0;
    int d = (int)(i2 / (G4 * 1536));
    int rem = (int)(i2 % (long)(G4 * 1536));
    int g = rem / 1536, k = rem % 1536;
    float v = (k < 1024) ? loadIn(wih1, ((long)d * G4 + g) * 1024 + k, bf)
                         : loadIn(whh1, ((long)d * G4 + g) * 512 + (k - 1024), bf);
    Wc1[i2] = f2bf(v);
  } else if (idx < N0 + N1 + NB2) {
    long i3 = idx - N0 - N1;  // [layer][d][g]
    int layer = (int)(i3 / (2 * G4));
    int d = (int)((i3 / G4) & 1);
    int g = (int)(i3 % G4);
    const void* bb = layer ? b1 : b0;
    float v = loadIn(bb, (long)d * 2 * G4 + g, bf) +
              loadIn(bb, (long)d * 2 * G4 + G4 + g, bf);
    bsum[i3] = v;
  } else if (idx < N0 + N1 + NB2 + 4096) {
    int n = (int)(idx - N0 - N1 - NB2);  // [0,4096): G[0] bias row
    int d = n >> 11, loc = n & 2047;
    int colb = loc >> 7, rr = loc & 127;
    int jn = rr >> 2, g = rr & 3;
    int grow = g * 512 + colb * 32 + jn;
    float v = loadIn(b0, (long)d * 2 * G4 + grow, bf) +
              loadIn(b0, (long)d * 2 * G4 + G4 + grow, bf);
    G[n] = f2bf(v);
  }
}

// ---------------- zero the barrier (8 KB) ----------------
__global__ void zero_bar(unsigned int* bar) {
  bar[blockIdx.x * 256 + threadIdx.x] = 0u;
}

// ---------------- G GEMM: G[1+v] = tableT[v] @ Wih0^T + bias --------------
// layer-0 x-gates depend on the token only through q (12001 distinct
// values) -- compute per-VOCAB-ROW gates once (50 GF) instead of per-token.
// G row layout: [d 2][colb 16][jn*4+g 128] (matches lstm xgv gather).
__global__ __launch_bounds__(256, 3) void g_gemm(
    const u16* __restrict__ tableT, const u16* __restrict__ Wc,
    const float* __restrict__ bsumL, u16* __restrict__ G) {
  __shared__ __align__(16) char lds[32768];  // A 16K + B 16K
  const int tid = threadIdx.x;
  const int lane = tid & 63, wv = tid >> 6;
  const int wm = wv & 1, wn = wv >> 1;
  const int col = lane & 15, quad = lane >> 4;
  const int bx = blockIdx.x >> 5;  // 0..93
  const int by = blockIdx.x & 31;
  const int tb0 = bx * 128;  // vocab row base
  const int d = by >> 4, colb = by & 15, j0 = colb * 32;

  f32x4 zero = {0.f, 0.f, 0.f, 0.f};
  f32x4 acc[4][4];
#pragma unroll
  for (int i = 0; i < 4; ++i)
#pragma unroll
    for (int j = 0; j < 4; ++j) acc[i][j] = zero;

  for (int it = 0; it < 8; ++it) {
    int k0 = it << 6;
#pragma unroll
    for (int p = 0; p < 8; ++p) {
      int c = p * 256 + tid;  // [0,2048)
      const u16* gsrc;
      if (c < 1024) {  // A rows (vocab)
        int r = c >> 3, sl = c & 7;
        int kk = k0 + ((sl * 8) ^ ((r & 7) << 3));
        gsrc = tableT + (long)(tb0 + r) * 512 + kk;
      } else {
        int cb = c - 1024;
        int r = cb >> 3, sl = cb & 7;
        int kk = k0 + ((sl * 8) ^ ((r & 7) << 3));
        int grow = (r >> 5) * 512 + j0 + (r & 31);
        gsrc = Wc + ((long)d * G4 + grow) * 1024 + kk;  // wih part (k<512)
      }
      __builtin_amdgcn_global_load_lds(
          (const __attribute__((address_space(1))) void*)(const void*)gsrc,
          (__attribute__((address_space(3))) void*)(lds + p * 4096 + wv * 1024),
          16, 0, 0);
    }
    __syncthreads();
    const u16* As = (const u16*)lds;
    const u16* Bs = (const u16*)(lds + 16384);
#pragma unroll
    for (int ks = 0; ks < 2; ++ks) {
      short8 afr[4], bfr[4];
#pragma unroll
      for (int mf = 0; mf < 4; ++mf) {
        int rm = wm * 64 + mf * 16 + col;
        int sl = (ks * 32 + quad * 8) ^ ((rm & 7) << 3);
        afr[mf] = *(const short8*)(As + rm * 64 + sl);
      }
#pragma unroll
      for (int nf = 0; nf < 4; ++nf) {
        int br = wn * 64 + nf * 16 + col;
        int sl = (ks * 32 + quad * 8) ^ ((br & 7) << 3);
        bfr[nf] = *(const short8*)(Bs + br * 64 + sl);
      }
#pragma unroll
      for (int mf = 0; mf < 4; ++mf)
#pragma unroll
        for (int nf = 0; nf < 4; ++nf)
          acc[mf][nf] = __builtin_amdgcn_mfma_f32_16x16x32_bf16(
              afr[mf], bfr[nf], acc[mf][nf], 0, 0, 0);
    }
    __syncthreads();
  }

  float bias[4];
#pragma unroll
  for (int nf = 0; nf < 4; ++nf) {
    int n = wn * 64 + nf * 16 + col;
    bias[nf] = bsumL[d * G4 + (n >> 5) * 512 + j0 + (n & 31)];
  }
#pragma unroll
  for (int mf = 0; mf < 4; ++mf)
#pragma unroll
    for (int nf = 0; nf < 4; ++nf) {
      int n = wn * 64 + nf * 16 + col;
      int g = n >> 5, jn = n & 31;
#pragma unroll
      for (int r = 0; r < 4; ++r) {
        int m = wm * 64 + mf * 16 + quad * 4 + r;
        int v = tb0 + m;
        if (v < NV)
          G[(long)(v + 1) * 4096 + ((d * 16 + colb) << 7) + jn * 4 + g] =
              f2bf(acc[mf][nf][r] + bias[nf]);
      }
    }
}

// ---------------- xg GEMM (layer 1): xg[t][d][col][b][jn*4+g] -------------
// 128x128 tile, BK=64, m97-style staging, 4 waves 2x2; supertile swizzle.
__global__ __launch_bounds__(256, 3) void xg_gemm(
    const u16* __restrict__ X, int Kx, int Kfull, const u16* __restrict__ Wc,
    const float* __restrict__ bsumL, u16* __restrict__ xg) {
  __shared__ __align__(16) char lds[32768];  // A 16K + B 16K
  const int tid = threadIdx.x;
  const int lane = tid & 63, wv = tid >> 6;
  const int wm = wv & 1, wn = wv >> 1;
  const int col = lane & 15, quad = lane >> 4;
  const int s = blockIdx.x >> 5, w = blockIdx.x & 31;
  const int bx = (s % 40) * 4 + (w & 3);
  const int by = (s / 40) * 8 + (w >> 2);
  const int tb0 = bx * 128;
  const int d = by >> 4, colb = by & 15, j0 = colb * 32;

  f32x4 zero = {0.f, 0.f, 0.f, 0.f};
  f32x4 acc[4][4];
#pragma unroll
  for (int i = 0; i < 4; ++i)
#pragma unroll
    for (int j = 0; j < 4; ++j) acc[i][j] = zero;

  const int iters = Kx >> 6;
  for (int it = 0; it < iters; ++it) {
    int k0 = it << 6;
#pragma unroll
    for (int p = 0; p < 8; ++p) {
      int c = p * 256 + tid;  // [0,2048)
      const u16* gsrc;
      if (c < 1024) {  // A rows 0..127
        int r = c >> 3, sl = c & 7;
        int kk = k0 + ((sl * 8) ^ ((r & 7) << 3));
        gsrc = X + (long)(tb0 + r) * Kx + kk;
      } else {
        int cb = c - 1024;
        int r = cb >> 3, sl = cb & 7;
        int kk = k0 + ((sl * 8) ^ ((r & 7) << 3));
        int grow = (r >> 5) * 512 + j0 + (r & 31);
        gsrc = Wc + ((long)d * G4 + grow) * Kfull + kk;
      }
      __builtin_amdgcn_global_load_lds(
          (const __attribute__((address_space(1))) void*)(const void*)gsrc,
          (__attribute__((address_space(3))) void*)(lds + p * 4096 + wv * 1024),
          16, 0, 0);
    }
    __syncthreads();
    const u16* As = (const u16*)lds;
    const u16* Bs = (const u16*)(lds + 16384);
#pragma unroll
    for (int ks = 0; ks < 2; ++ks) {
      short8 afr[4], bfr[4];
#pragma unroll
      for (int mf = 0; mf < 4; ++mf) {
        int rm = wm * 64 + mf * 16 + col;
        int sl = (ks * 32 + quad * 8) ^ ((rm & 7) << 3);
        afr[mf] = *(const short8*)(As + rm * 64 + sl);
      }
#pragma unroll
      for (int nf = 0; nf < 4; ++nf) {
        int br = wn * 64 + nf * 16 + col;
        int sl = (ks * 32 + quad * 8) ^ ((br & 7) << 3);
        bfr[nf] = *(const short8*)(Bs + br * 64 + sl);
      }
#pragma unroll
      for (int mf = 0; mf < 4; ++mf)
#pragma unroll
        for (int nf = 0; nf < 4; ++nf)
          acc[mf][nf] = __builtin_amdgcn_mfma_f32_16x16x32_bf16(
              afr[mf], bfr[nf], acc[mf][nf], 0, 0, 0);
    }
    __syncthreads();
  }

  float bias[4];
#pragma unroll
  for (int nf = 0; nf < 4; ++nf) {
    int n = wn * 64 + nf * 16 + col;
    bias[nf] = bsumL[d * G4 + (n >> 5) * 512 + j0 + (n & 31)];
  }
#pragma unroll
  for (int mf = 0; mf < 4; ++mf)
#pragma unroll
    for (int nf = 0; nf < 4; ++nf) {
      int n = wn * 64 + nf * 16 + col;
      int g = n >> 5, jn = n & 31;
#pragma unroll
      for (int r = 0; r < 4; ++r) {
        int m = wm * 64 + mf * 16 + quad * 4 + r;
        int tb = tb0 + m, t = tb >> 9, b = tb & 511;
        long oi = ((((long)t * 2 + d) * 16 + colb) * 512 + b) * 128 + jn * 4 + g;
        xg[oi] = f2bf(acc[mf][nf][r] + bias[nf]);
      }
    }
}

// ---------------- persistent bidirectional LSTM recurrence ----------------
// R16 = R15 with ONE exposed stage wait instead of two.
// Mechanism: Whh's first 128 k-columns move to REGISTERS (B-frags are
// per-lane: 4 g x 4 chunks x short8 = 64 VGPR; occupancy is LDS-bound at
// 1 block/CU so VGPR is free). Whh LDS shrinks to 128 rows x 384 k = 96 KB
// (chunk-major [cc 6][row 128][64k swz]), freeing a single 64 KB stage
// buffer for the WHOLE h tile (64 rows x 512 k): all 16 gload_lds issued
// back-to-back, ONE vmcnt(0) barrier, then 128 MFMA/wave with no mid-loop
// barriers. 5 barriers/step (was 7), 1 exposed LLC wait (was 2).
// Swizzle: same involution on source-k and read-offset for both regions.
__global__ __launch_bounds__(256, 1) void lstm_pers(
    const u16* __restrict__ xg, const int* __restrict__ qv,
    const u16* __restrict__ Wc, int Kfull, int Kx, u16* __restrict__ hbuf,
    u16* __restrict__ h0cat, void* __restrict__ outp,
    const int* __restrict__ qlen, const int* __restrict__ flag,
    unsigned int* bar, int layer) {
  __shared__ __align__(16) char lds[163840];  // [Whh 96K][h-stage 64K]
  const int tid = threadIdx.x;
  const int lane = tid & 63, wv = tid >> 6;
  const int wm = wv & 1, wn = wv >> 1;
  const int col = lane & 15, quad = lane >> 4;
  const int l = blockIdx.x;
  const int colid = l & 31, mi = l >> 5;
  const int colb = colid & 15, j0 = colb * 32, d = colid >> 4;
  const int m0 = mi * 64;
  const int gid = l >> 4;  // == mi*2 + d (16 groups of 16 blocks)

  // ---- preload Whh k in [128,512) into LDS: [cc 6][row 128][64k swz] ----
  // row r = g*32+jn holds W row g*512+j0+jn. 96 KB = 24 iters x 4 KB.
#pragma unroll
  for (int p = 0; p < 24; ++p) {
    int c = p * 256 + tid;  // [0,6144)
    int cc = c >> 10, row = (c >> 3) & 127, sl = c & 7;
    int grow = (row >> 5) * 512 + j0 + (row & 31);
    int gk = Kx + 128 + cc * 64 + ((sl * 8) ^ ((row & 7) << 3));
    const u16* gsrc = Wc + ((long)d * G4 + grow) * Kfull + gk;
    __builtin_amdgcn_global_load_lds(
        (const __attribute__((address_space(1))) void*)(const void*)gsrc,
        (__attribute__((address_space(3))) void*)(lds + p * 4096 + wv * 1024),
        16, 0, 0);
  }
  const u16* WhhB = (const u16*)lds;  // u16 offset: cc*8192 + row*64 + kslot
  char* hstg = lds + 98304;           // 64 KB full-h stage [64 rows][512 k swz]
  u16* hLDS = (u16*)hstg;             // epilogue pack [64 m][32 jn] aliases

  // ---- Whh k in [0,128) as per-lane B-fragments: breg[g][chunk] ----
  short8 breg[4][4];
#pragma unroll
  for (int g = 0; g < 4; ++g) {
    int grow = g * 512 + j0 + wn * 16 + col;
    const u16* wp = Wc + ((long)d * G4 + grow) * Kfull + Kx;
#pragma unroll
    for (int c4 = 0; c4 < 4; ++c4)
      breg[g][c4] = *(const short8*)(wp + c4 * 32 + quad * 8);
  }

  float creg[2][4];
#pragma unroll
  for (int i = 0; i < 2; ++i)
#pragma unroll
    for (int r = 0; r < 4; ++r) creg[i][r] = 0.f;
  const int isbf = *flag;
  f32x4 zero = {0.f, 0.f, 0.f, 0.f};

  __syncthreads();  // Whh resident

#pragma unroll 1
  for (int t = 0; t < NW; ++t) {
    const int tq = d ? (NW - 1 - t) : t;

    // x-gate prefetch (issued before the poll)
    ushort4 xgv[2][4];
    if (layer == 0) {
#pragma unroll
      for (int mf = 0; mf < 2; ++mf)
#pragma unroll
        for (int r = 0; r < 4; ++r) {
          int m = wm * 32 + mf * 16 + quad * 4 + r;
          int q = qv[(m0 + m) * NW + tq];
          xgv[mf][r] = *(const ushort4*)(xg + (long)q * 4096 +
                                         ((d * 16 + colb) << 7) +
                                         (wn * 16 + col) * 4);
        }
    } else {
      const u16* xgt =
          xg + ((((long)tq * 2 + d) * 16 + colb) * 512 + m0) * 128;
#pragma unroll
      for (int mf = 0; mf < 2; ++mf)
#pragma unroll
        for (int r = 0; r < 4; ++r) {
          int m = wm * 32 + mf * 16 + quad * 4 + r;
          xgv[mf][r] = *(const ushort4*)(xgt + m * 128 + (wn * 16 + col) * 4);
        }
    }

    f32x4 acc[2][4];  // [mf][gate]
#pragma unroll
    for (int i = 0; i < 2; ++i)
#pragma unroll
      for (int j = 0; j < 4; ++j) acc[i][j] = zero;

    if (t > 0) {
      // ---- per-writer slot poll: all 16 writers of (mi,d) signaled t ----
      if (wv == 0) {
        u32* sp = bar + gid * 16 + (lane & 15);
        while (__ballot((int)(__hip_atomic_load(sp, __ATOMIC_RELAXED,
                                                __HIP_MEMORY_SCOPE_AGENT) <
                              (u32)t)))
          __builtin_amdgcn_s_sleep(1);
      }
      __syncthreads();

      const u16* hp =
          hbuf + ((t - 1) & 1) * (2L * NB * NH) + ((long)d * NB + m0) * NH;
      // ---- stage the FULL 64 rows x 512 k = 64 KB in one shot, SC1 ----
#pragma unroll
      for (int p = 0; p < 16; ++p) {
        int c = p * 256 + tid;  // [0,4096)
        int row = c >> 6, slot = c & 63;
        int kk = (slot >> 3) * 64 + (((slot & 7) * 8) ^ ((row & 7) << 3));
        const u16* gsrc = hp + (long)row * NH + kk;
        __builtin_amdgcn_global_load_lds(
            (const __attribute__((address_space(1))) void*)(const void*)gsrc,
            (__attribute__((address_space(3))) void*)(hstg + p * 4096 +
                                                      wv * 1024),
            16, 0, 16 /* SC1: agent-coherent read from LLC */);
      }
      __syncthreads();  // all h resident (the ONE exposed LLC wait)

      const u16* As = (const u16*)hstg;
#pragma unroll
      for (int ks = 0; ks < 16; ++ks) {
        const int ksub = ks * 32 + quad * 8;  // [0,512)
        short8 afr[2];
#pragma unroll
        for (int mf = 0; mf < 2; ++mf) {
          int rm = wm * 32 + mf * 16 + col;
          afr[mf] = *(const short8*)(As + rm * 512 + (ksub & ~63) +
                                     ((ksub & 63) ^ ((rm & 7) << 3)));
        }
#pragma unroll
        for (int g = 0; g < 4; ++g) {
          short8 bfr;
          if (ks < 4) {
            bfr = breg[g][ks];  // k < 128 from registers
          } else {
            int br = g * 32 + wn * 16 + col;
            int kp = ksub - 128;  // [0,384)
            bfr = *(const short8*)(WhhB + (kp >> 6) * 8192 + br * 64 +
                                   ((kp & 63) ^ ((br & 7) << 3)));
          }
#pragma unroll
          for (int mf = 0; mf < 2; ++mf)
            acc[mf][g] = __builtin_amdgcn_mfma_f32_16x16x32_bf16(
                afr[mf], bfr, acc[mf][g], 0, 0, 0);
        }
      }
      __syncthreads();  // all A-reads done -> pack (aliases hstg) safe
    }

    // ---- register-only cell update; pack h into 4 KB LDS ----
#pragma unroll
    for (int mf = 0; mf < 2; ++mf)
#pragma unroll
      for (int r = 0; r < 4; ++r) {
        int m = wm * 32 + mf * 16 + quad * 4 + r;
        const u16* xv = (const u16*)&xgv[mf][r];
        float gi = acc[mf][0][r] + bf2f(xv[0]);
        float gf = acc[mf][1][r] + bf2f(xv[1]);
        float gg = acc[mf][2][r] + bf2f(xv[2]);
        float go = acc[mf][3][r] + bf2f(xv[3]);
        float si = sigm(gi);
        float sf = sigm(gf);
        float so = sigm(go);
        float cn = sf * creg[mf][r] + si * fast_tanh(gg);
        float h = so * fast_tanh(cn);
        creg[mf][r] = cn;
        hLDS[m * 32 + wn * 16 + col] = f2bf(h);
        // fp32 output path: store full-precision h directly (rare rows)
        if (layer == 1 && !isbf) {
          int bg = m0 + m;
          if (qlen[bg] - 1 == tq)
            ((float*)outp)[(long)bg * (2 * NH) + d * NH + j0 + wn * 16 + col] =
                h;
        }
      }
    __syncthreads();

    // ---- hbuf (LLC) stores; keep values in regs for deferred HBM stores --
    u16* hnxt = hbuf + (t & 1) * (2L * NB * NH);
    u32 hw[4];
    int bgp[4], jgp[4];
#pragma unroll
    for (int p = 0; p < 4; ++p) {
      int c = p * 256 + tid;  // [0,1024) pairs
      int m = c >> 4, pr = c & 15;
      hw[p] = ((const u32*)hLDS)[m * 16 + pr];
      bgp[p] = m0 + m;
      jgp[p] = j0 + pr * 2;
      __hip_atomic_store(
          (u32*)(hnxt + ((long)d * NB + bgp[p]) * NH + jgp[p]), hw[p],
          __ATOMIC_RELAXED, __HIP_MEMORY_SCOPE_AGENT);
    }

    // ---- drain hbuf stores, then signal own slot (non-blocking) ----
    if (t < NW - 1) {
      __syncthreads();  // drains vmcnt: hbuf stores visible at LLC
      if (tid == 0)
        __hip_atomic_store(bar + gid * 16 + colb, (u32)(t + 1),
                           __ATOMIC_RELAXED, __HIP_MEMORY_SCOPE_AGENT);
    }

    // ---- deferred HBM stores (off the rendezvous drain path) ----
#pragma unroll
    for (int p = 0; p < 4; ++p) {
      if (layer == 0) {
        *(u32*)(h0cat + ((long)tq * NB + bgp[p]) * (2 * NH) + d * NH +
                jgp[p]) = hw[p];
      } else if (isbf && qlen[bgp[p]] - 1 == tq) {
        *(u32*)((u16*)outp + (long)bgp[p] * (2 * NH) + d * NH + jgp[p]) =
            hw[p];
      }
    }
  }
}

extern "C" void kernel_launch(void* const* d_in, const int* in_sizes, int n_in,
                              void* d_out, int out_size, void* d_ws,
                              size_t ws_size, hipStream_t stream) {
  const int* qv = (const int*)d_in[0];
  const int* ql = (const int*)d_in[1];
  const void* lookup = d_in[2];
  const void* wih0 = d_in[3];
  const void* whh0 = d_in[4];
  const void* b0 = d_in[5];
  const void* wih1 = d_in[6];
  const void* whh1 = d_in[7];
  const void* b1 = d_in[8];

  char* ws = (char*)d_ws;
  size_t off = 0;
  int* flag = (int*)ws;                 off += 256;
  unsigned int* bar = (unsigned int*)(ws + off); off += 8192;
  float* bsum = (float*)(ws + off);     off += 2L * 2 * G4 * 4;        // 32 KB
  u16* Wc0 = (u16*)(ws + off);          off += 2L * G4 * 1024 * 2;     // 8 MB
  u16* Wc1 = (u16*)(ws + off);          off += 2L * G4 * 1536 * 2;     // 12 MB
  u16* hbuf = (u16*)(ws + off);         off += 2L * 2 * NB * NH * 2;   // 2 MB
  u16* h0cat = (u16*)(ws + off);        off += (size_t)NW * NB * 2 * NH * 2; // 40 MB
  u16* xg = (u16*)(ws + off);           off += (size_t)NW * 2 * 16 * 512 * 128 * 2; // 168 MB
  u16* tableT = h0cat;  // tableT (12.3 MB) aliases h0cat: dead before layer0
  u16* G = xg;  // G (98.3 MB) aliases xg: dead once layer-1 xg_gemm writes

  detect_kernel<<<1, 64, 0, stream>>>((const u16*)lookup, flag);
  table_kernel<<<dim3(188, 8), dim3(64, 4), 0, stream>>>(lookup, flag, tableT);
  {
    long total = 2L * G4 * 1024 + 2L * G4 * 1536 + 2L * 2 * G4 + 4096;
    int blocks = (int)((total + 255) / 256);
    pack_kernel<<<blocks, 256, 0, stream>>>(wih0, whh0, b0, wih1, whh1, b1,
                                            flag, Wc0, Wc1, bsum, G);
  }

  // layer 0: per-vocab gate GEMM + fused recurrence gather
  g_gemm<<<94 * 32, 256, 0, stream>>>(tableT, Wc0, bsum, G);
  zero_bar<<<8, 256, 0, stream>>>(bar);
  lstm_pers<<<256, 256, 0, stream>>>(G, qv, Wc0, 1024, 512, hbuf, h0cat,
                                     d_out, ql, flag, bar, 0);
  // layer 1
  xg_gemm<<<5120, 256, 0, stream>>>(h0cat, 1024, 1536, Wc1, bsum + 2 * G4, xg);
  zero_bar<<<8, 256, 0, stream>>>(bar);
  lstm_pers<<<256, 256, 0, stream>>>(xg, qv, Wc1, 1536, 1024, hbuf, h0cat,
                                     d_out, ql, flag, bar, 1);
}